// Round 2
// baseline (744.640 us; speedup 1.0000x reference)
//
#include <hip/hip_runtime.h>

// ---------------------------------------------------------------------------
// HieraWeatherEmbedding fused implementation (fp32 I/O, fp32 math,
// bf16 internal packing for LDS tiles and folded matrices)
//
// Algebraic folds (exact reassociation):
//  * group/ens queries are constant => score = dot(Wk^T q, xe) + q.bk
//    (K projection never materialized)
//  * softmax weights sum to 1 =>
//    out = sum_h M_h @ (sum_g a_g * xe_g) + c,  M_h = Wout[:,h] @ Wv[h,:]
// ---------------------------------------------------------------------------

#define NG 12

__constant__ int GOFF[13] = {0,7,14,21,28,35,44,53,62,71,80,97,103};
__constant__ int GSLOT[103] = {
  3,8,13,18,23,28,33,
  4,9,14,19,24,29,34,
  2,7,12,17,22,27,32,
  1,6,11,16,21,26,31,
  0,5,10,15,20,25,30,
  3,8,13,18,23,28,33,38,43,
  4,9,14,19,24,29,34,39,44,
  2,7,12,17,22,27,32,37,42,
  1,6,11,16,21,26,31,36,41,
  0,5,10,15,20,25,30,35,40,
  45,46,47,48,49,50,51,52,53,54,55,56,57,58,59,60,61,
  62,63,64,65,66,67};

// workspace layout (float offsets for the fp32 region)
#define QK_GRP 0        // [12][2][128]
#define QK_ENS 3072     // [12][2][128]
#define QB_GRP 6144     // [12][2] (padded 32)
#define QB_ENS 6176     // [24]    (padded 32)
#define CGRP   6208     // [12][128]
#define CENS   7744     // [128]
#define QF_GRP 7872     // [12][128]
#define QF_ENS 9408     // [12][128]
#define MG_BYTE_OFF 43776    // ushort [12][2][64][128][2]  (e-paired, r-major)
#define ME_BYTE_OFF 830208   // ushort [2][64][128][2]

__device__ __forceinline__ float bf2f(unsigned short s) {
  return __uint_as_float(((unsigned)s) << 16);
}
__device__ __forceinline__ unsigned short f2bf(float f) {
  unsigned u = __float_as_uint(f);
  u += 0x7fffu + ((u >> 16) & 1u);
  return (unsigned short)(u >> 16);
}

// ---------------------------------------------------------------------------
// Precompute 1: q_full vectors and folded bias vectors (runs every launch)
// ---------------------------------------------------------------------------
__global__ void hwe_pre1(const float* __restrict__ giw,
                         const float* __restrict__ gib,
                         const float* __restrict__ gow,
                         const float* __restrict__ gob,
                         const float* __restrict__ cq,
                         const float* __restrict__ eq,
                         const float* __restrict__ eiw,
                         const float* __restrict__ eib,
                         const float* __restrict__ eow,
                         const float* __restrict__ eob,
                         float* __restrict__ wsf) {
  int blk = blockIdx.x;
  int d = threadIdx.x;  // 0..127
  if (blk < 12) {                       // q_full for groups
    int i = blk;
    float acc = gib[i*384 + d];
    for (int e = 0; e < 128; ++e)
      acc += giw[i*49152 + d*128 + e] * cq[i*128 + e];
    wsf[QF_GRP + i*128 + d] = acc;
  } else if (blk < 24) {                // c_grp = Wout@bv + bout
    int i = blk - 12;
    float acc = gob[i*128 + d];
    for (int k = 0; k < 128; ++k)
      acc += gow[i*16384 + d*128 + k] * gib[i*384 + 256 + k];
    wsf[CGRP + i*128 + d] = acc;
  } else if (blk < 36) {                // q_full for ensemble queries
    int t = blk - 24;
    float acc = eib[d];
    for (int e = 0; e < 128; ++e)
      acc += eiw[d*128 + e] * eq[t*128 + e];
    wsf[QF_ENS + t*128 + d] = acc;
  } else {                              // c_ens
    float acc = eob[d];
    for (int k = 0; k < 128; ++k)
      acc += eow[d*128 + k] * eib[256 + k];
    wsf[CENS + d] = acc;
  }
}

// ---------------------------------------------------------------------------
// Precompute 2: folded query-key vectors qk = Wk^T q (per head) + qb = q.bk
// ---------------------------------------------------------------------------
__global__ void hwe_pre2(const float* __restrict__ giw,
                         const float* __restrict__ gib,
                         const float* __restrict__ eiw,
                         const float* __restrict__ eib,
                         float* __restrict__ wsf) {
  int blk = blockIdx.x;
  int e = threadIdx.x;  // 0..127
  if (blk < 24) {
    int i = blk >> 1, h = blk & 1;
    float acc = 0.f;
    for (int dp = 0; dp < 64; ++dp)
      acc += wsf[QF_GRP + i*128 + h*64 + dp] *
             giw[i*49152 + (128 + h*64 + dp)*128 + e];
    wsf[QK_GRP + (i*2 + h)*128 + e] = acc;
    if (e == 0) {
      float ab = 0.f;
      for (int dp = 0; dp < 64; ++dp)
        ab += wsf[QF_GRP + i*128 + h*64 + dp] * gib[i*384 + 128 + h*64 + dp];
      wsf[QB_GRP + i*2 + h] = ab;
    }
  } else {
    int tb = blk - 24;
    int t = tb >> 1, h = tb & 1;
    float acc = 0.f;
    for (int dp = 0; dp < 64; ++dp)
      acc += wsf[QF_ENS + t*128 + h*64 + dp] *
             eiw[(128 + h*64 + dp)*128 + e];
    wsf[QK_ENS + (t*2 + h)*128 + e] = acc;
    if (e == 0) {
      float ab = 0.f;
      for (int dp = 0; dp < 64; ++dp)
        ab += wsf[QF_ENS + t*128 + h*64 + dp] * eib[128 + h*64 + dp];
      wsf[QB_ENS + t*2 + h] = ab;
    }
  }
}

// ---------------------------------------------------------------------------
// Precompute 3: folded M matrices, bf16, transposed [e][r] with e paired
// ---------------------------------------------------------------------------
__global__ void hwe_pre3(const float* __restrict__ giw,
                         const float* __restrict__ gow,
                         const float* __restrict__ eiw,
                         const float* __restrict__ eow,
                         unsigned short* __restrict__ Mg,
                         unsigned short* __restrict__ Me) {
  int blk = blockIdx.x;
  int r = threadIdx.x;  // 0..127
  if (blk < 1536) {
    int e2 = blk & 63, h = (blk >> 6) & 1, i = blk >> 7;
    float m0 = 0.f, m1 = 0.f;
    for (int dp = 0; dp < 64; ++dp) {
      float wo = gow[i*16384 + r*128 + h*64 + dp];
      m0 += wo * giw[i*49152 + (256 + h*64 + dp)*128 + 2*e2];
      m1 += wo * giw[i*49152 + (256 + h*64 + dp)*128 + 2*e2 + 1];
    }
    int base = (((i*2 + h)*64) + e2)*256 + 2*r;
    Mg[base] = f2bf(m0);
    Mg[base + 1] = f2bf(m1);
  } else {
    int bb = blk - 1536;
    int e2 = bb & 63, h = bb >> 6;
    float m0 = 0.f, m1 = 0.f;
    for (int dp = 0; dp < 64; ++dp) {
      float wo = eow[r*128 + h*64 + dp];
      m0 += wo * eiw[(256 + h*64 + dp)*128 + 2*e2];
      m1 += wo * eiw[(256 + h*64 + dp)*128 + 2*e2 + 1];
    }
    int base = ((h*64) + e2)*256 + 2*r;
    Me[base] = f2bf(m0);
    Me[base + 1] = f2bf(m1);
  }
}

// ---------------------------------------------------------------------------
// Main fused kernel: embed -> group attn -> ensemble attn -> LayerNorm
// grid 2048, block 256, Tn = 4 patches per block
// ---------------------------------------------------------------------------
// LDS layout (bytes), total 48192:
//   phase-B region (overlaid by phase-C region):
//     0     xp    float [68][2][8]           4352
//     4352  xe    ushort [(nn*G+g)*132+e]    17952
//     22304 qk    float [2][128]             1024
//     23328 qb    float [2]                  (pad to 23344)
//     23344 sc    float [(nn*17+g)*2+h]      544   -> end 23888
//   phase-C overlay (starts at 0):
//     0     qke   float [24][129]            12384
//     12384 qbe   float [24]                 96
//     12480 sce   float [((nn*2+h)*12+t)*12+s] 4608
//     17088 rbuf  ushort [4][1536]           12288 -> end 29376
//   persistent:
//     29376 xbar  float [(h*128+e)*4+nn]     4096
//     33472 part  float [4][128]             2048
//     35520 outg  ushort [(nn*12+i)*132+r]   12672 -> end 48192
__global__ __launch_bounds__(256) void hwe_main(
    const float* __restrict__ x,
    const float* __restrict__ conv_w,
    const float* __restrict__ conv_b,
    const float* __restrict__ chem,
    const float* __restrict__ lgam,
    const float* __restrict__ lbet,
    const float* __restrict__ wsf,
    const unsigned short* __restrict__ Mg,
    const unsigned short* __restrict__ Me,
    float* __restrict__ out) {
  __shared__ __align__(16) char smem[48192];
  float* xp = (float*)(smem + 0);
  unsigned short* xe = (unsigned short*)(smem + 4352);
  float* qk = (float*)(smem + 22304);
  float* qb = (float*)(smem + 23328);
  float* sc = (float*)(smem + 23344);
  float* qke = (float*)(smem + 0);
  float* qbe = (float*)(smem + 12384);
  float* sce = (float*)(smem + 12480);
  unsigned short* rbuf = (unsigned short*)(smem + 17088);
  float* xbar = (float*)(smem + 29376);
  float* part = (float*)(smem + 33472);
  unsigned short* outg = (unsigned short*)(smem + 35520);

  const int tid = threadIdx.x;
  const int b = blockIdx.x;
  const int hi = b >> 5;            // 0..63
  const int wib = (b & 31) << 2;    // 0..124 step 4
  const int nbase = hi * 128 + wib;

  // ---- Phase A: load 2x2 patch pixels for the 68 used channels ----
  for (int idx = tid; idx < 68 * 16; idx += 256) {
    int s = idx >> 4;
    int r = (idx >> 3) & 1;
    int c = idx & 7;
    int v = (s < 45) ? s : s + 20;
    xp[(s*2 + r)*8 + c] = x[(v*128 + 2*hi + r)*256 + 2*wib + c];
  }
  __syncthreads();

  // ---- Phase B: 12 groups ----
  for (int gi = 0; gi < NG; ++gi) {
    const int goff = GOFF[gi];
    const int G = GOFF[gi + 1] - goff;

    qk[tid] = wsf[QK_GRP + gi*256 + tid];
    if (tid < 2) qb[tid] = wsf[QB_GRP + gi*2 + tid];

    // embed the group's channels: xe[nn][g][e]
    for (int idx = tid; idx < G*128; idx += 256) {
      int g = idx >> 7;
      int e = idx & 127;
      int slot = GSLOT[goff + g];
      int v = (slot < 45) ? slot : slot + 20;
      float cw0 = conv_w[(v*4 + 0)*128 + e];
      float cw1 = conv_w[(v*4 + 1)*128 + e];
      float cw2 = conv_w[(v*4 + 2)*128 + e];
      float cw3 = conv_w[(v*4 + 3)*128 + e];
      float base = conv_b[v*128 + e] + chem[v*128 + e];
      const float* xp0 = &xp[slot*16];
#pragma unroll
      for (int nn = 0; nn < 4; ++nn) {
        float val = base + xp0[2*nn]*cw0 + xp0[2*nn + 1]*cw1 +
                    xp0[8 + 2*nn]*cw2 + xp0[8 + 2*nn + 1]*cw3;
        xe[(nn*G + g)*132 + e] = f2bf(val);
      }
    }
    __syncthreads();

    // scores: dot(qk[h], xe[nn][g]) + qb[h]
    if (tid < 8*G) {
      int g = tid % G;
      int h = (tid / G) & 1;
      int nn = tid / (2*G);
      const float* qr = &qk[h*128];
      const unsigned short* xr = &xe[(nn*G + g)*132];
      float acc = qb[h];
#pragma unroll 8
      for (int e = 0; e < 128; ++e) acc += qr[e] * bf2f(xr[e]);
      sc[(nn*17 + g)*2 + h] = acc * 0.125f;
    }
    __syncthreads();

    // softmax over g (per nn,h)
    if (tid < 8) {
      int nn = tid >> 1, h = tid & 1;
      float m = -1e30f;
      for (int g = 0; g < G; ++g) m = fmaxf(m, sc[(nn*17 + g)*2 + h]);
      float ssum = 0.f;
      for (int g = 0; g < G; ++g) {
        float ev = __expf(sc[(nn*17 + g)*2 + h] - m);
        sc[(nn*17 + g)*2 + h] = ev;
        ssum += ev;
      }
      float inv = 1.0f / ssum;
      for (int g = 0; g < G; ++g) sc[(nn*17 + g)*2 + h] *= inv;
    }
    __syncthreads();

    // xbar[h][e][nn] = sum_g a * xe
    for (int idx = tid; idx < 1024; idx += 256) {
      int e = idx & 127;
      int h = (idx >> 7) & 1;
      int nn = idx >> 8;
      float acc = 0.f;
      for (int g = 0; g < G; ++g)
        acc += sc[(nn*17 + g)*2 + h] * bf2f(xe[(nn*G + g)*132 + e]);
      xbar[(h*128 + e)*4 + nn] = acc;
    }
    __syncthreads();

    // folded matvec: out = M0@xbar0 + M1@xbar1 + c
    {
      int h = tid >> 7;
      int r = tid & 127;
      float a0 = 0.f, a1 = 0.f, a2 = 0.f, a3 = 0.f;
      const unsigned* mrow = (const unsigned*)Mg + ((gi*2 + h)*64)*128 + r;
      const float* xb = xbar + h*512;
#pragma unroll 4
      for (int e2 = 0; e2 < 64; ++e2) {
        unsigned mm = mrow[e2*128];
        float m0 = __uint_as_float(mm << 16);
        float m1 = __uint_as_float(mm & 0xffff0000u);
        float4 va = *(const float4*)(xb + 8*e2);
        float4 vb = *(const float4*)(xb + 8*e2 + 4);
        a0 += m0*va.x + m1*vb.x;
        a1 += m0*va.y + m1*vb.y;
        a2 += m0*va.z + m1*vb.z;
        a3 += m0*va.w + m1*vb.w;
      }
      if (h == 0) {
        part[r] = a0; part[128 + r] = a1; part[256 + r] = a2; part[384 + r] = a3;
      }
      __syncthreads();
      if (h == 1) {
        float c = wsf[CGRP + gi*128 + r];
        outg[(0*12 + gi)*132 + r] = f2bf(part[r]       + a0 + c);
        outg[(1*12 + gi)*132 + r] = f2bf(part[128 + r] + a1 + c);
        outg[(2*12 + gi)*132 + r] = f2bf(part[256 + r] + a2 + c);
        outg[(3*12 + gi)*132 + r] = f2bf(part[384 + r] + a3 + c);
      }
      __syncthreads();
    }
  }

  // ---- Phase C: ensemble attention ----
  for (int idx = tid; idx < 3072; idx += 256) {
    int th = idx >> 7;
    int e = idx & 127;
    qke[th*129 + e] = wsf[QK_ENS + idx];
  }
  if (tid < 24) qbe[tid] = wsf[QB_ENS + tid];
  __syncthreads();

  // scores over (nn,h,t,s)
  for (int idx = tid; idx < 1152; idx += 256) {
    int s = idx % 12;
    int t = (idx / 12) % 12;
    int h = (idx / 144) & 1;
    int nn = idx / 288;
    const float* qr = &qke[(t*2 + h)*129];
    const unsigned short* orow = &outg[(nn*12 + s)*132];
    float acc = qbe[t*2 + h];
#pragma unroll 8
    for (int e = 0; e < 128; ++e) acc += qr[e] * bf2f(orow[e]);
    sce[((nn*2 + h)*12 + t)*12 + s] = acc * 0.125f;
  }
  __syncthreads();

  // softmax over s
  if (tid < 96) {
    float* row = &sce[tid*12];
    float m = -1e30f;
    for (int s = 0; s < 12; ++s) m = fmaxf(m, row[s]);
    float ssum = 0.f;
    for (int s = 0; s < 12; ++s) {
      float ev = __expf(row[s] - m);
      row[s] = ev;
      ssum += ev;
    }
    float inv = 1.0f / ssum;
    for (int s = 0; s < 12; ++s) row[s] *= inv;
  }
  __syncthreads();

  // per ensemble query t: weighted sum then folded matvec
  for (int t = 0; t < 12; ++t) {
    for (int idx = tid; idx < 1024; idx += 256) {
      int nn = idx & 3;
      int e = (idx >> 2) & 127;
      int h = idx >> 9;
      const float* arow = &sce[((nn*2 + h)*12 + t)*12];
      float acc = 0.f;
#pragma unroll
      for (int s = 0; s < 12; ++s) acc += arow[s] * bf2f(outg[(nn*12 + s)*132 + e]);
      xbar[idx] = acc;  // layout (h*128+e)*4+nn == idx
    }
    __syncthreads();
    {
      int h = tid >> 7;
      int r = tid & 127;
      float a0 = 0.f, a1 = 0.f, a2 = 0.f, a3 = 0.f;
      const unsigned* mrow = (const unsigned*)Me + (h*64)*128 + r;
      const float* xb = xbar + h*512;
#pragma unroll 4
      for (int e2 = 0; e2 < 64; ++e2) {
        unsigned mm = mrow[e2*128];
        float m0 = __uint_as_float(mm << 16);
        float m1 = __uint_as_float(mm & 0xffff0000u);
        float4 va = *(const float4*)(xb + 8*e2);
        float4 vb = *(const float4*)(xb + 8*e2 + 4);
        a0 += m0*va.x + m1*vb.x;
        a1 += m0*va.y + m1*vb.y;
        a2 += m0*va.z + m1*vb.z;
        a3 += m0*va.w + m1*vb.w;
      }
      if (h == 0) {
        part[r] = a0; part[128 + r] = a1; part[256 + r] = a2; part[384 + r] = a3;
      }
      __syncthreads();
      if (h == 1) {
        float c = wsf[CENS + r];
        rbuf[0*1536 + t*128 + r] = f2bf(part[r]       + a0 + c);
        rbuf[1*1536 + t*128 + r] = f2bf(part[128 + r] + a1 + c);
        rbuf[2*1536 + t*128 + r] = f2bf(part[256 + r] + a2 + c);
        rbuf[3*1536 + t*128 + r] = f2bf(part[384 + r] + a3 + c);
      }
      __syncthreads();
    }
  }

  // ---- LayerNorm over 1536, one wave per patch ----
  {
    int nn = tid >> 6;
    int l = tid & 63;
    int n = nbase + nn;
    float s1 = 0.f, s2 = 0.f;
    for (int j = l; j < 1536; j += 64) {
      float v = bf2f(rbuf[nn*1536 + j]);
      s1 += v;
      s2 += v*v;
    }
#pragma unroll
    for (int off = 32; off > 0; off >>= 1) {
      s1 += __shfl_down(s1, off);
      s2 += __shfl_down(s2, off);
    }
    s1 = __shfl(s1, 0);
    s2 = __shfl(s2, 0);
    float mean = s1 * (1.f / 1536.f);
    float var = s2 * (1.f / 1536.f) - mean*mean;
    float rstd = rsqrtf(var + 1e-5f);
    for (int j = l; j < 1536; j += 64) {
      float v = bf2f(rbuf[nn*1536 + j]);
      float o = (v - mean) * rstd * lgam[j] + lbet[j];
      out[n*1536 + j] = o;
    }
  }
}

// ---------------------------------------------------------------------------
extern "C" void kernel_launch(void* const* d_in, const int* in_sizes, int n_in,
                              void* d_out, int out_size, void* d_ws, size_t ws_size,
                              hipStream_t stream) {
  const float* x   = (const float*)d_in[0];
  const float* cw  = (const float*)d_in[1];
  const float* cb  = (const float*)d_in[2];
  const float* ce  = (const float*)d_in[3];
  const float* cq  = (const float*)d_in[4];
  const float* giw = (const float*)d_in[5];
  const float* gib = (const float*)d_in[6];
  const float* gow = (const float*)d_in[7];
  const float* gob = (const float*)d_in[8];
  const float* eq  = (const float*)d_in[9];
  const float* eiw = (const float*)d_in[10];
  const float* eib = (const float*)d_in[11];
  const float* eow = (const float*)d_in[12];
  const float* eob = (const float*)d_in[13];
  const float* lg  = (const float*)d_in[14];
  const float* lb  = (const float*)d_in[15];

  float* wsf = (float*)d_ws;
  unsigned short* Mg = (unsigned short*)((char*)d_ws + MG_BYTE_OFF);
  unsigned short* Me = (unsigned short*)((char*)d_ws + ME_BYTE_OFF);

  hwe_pre1<<<37, 128, 0, stream>>>(giw, gib, gow, gob, cq, eq, eiw, eib, eow, eob, wsf);
  hwe_pre2<<<48, 128, 0, stream>>>(giw, gib, eiw, eib, wsf);
  hwe_pre3<<<1664, 128, 0, stream>>>(giw, gow, eiw, eow, Mg, Me);
  hwe_main<<<2048, 256, 0, stream>>>(x, cw, cb, ce, lg, lb, wsf, Mg, Me,
                                     (float*)d_out);
}

// Round 4
// 305.151 us; speedup vs baseline: 2.4402x; 2.4402x over previous
//
#include <hip/hip_runtime.h>

// ---------------------------------------------------------------------------
// HieraWeatherEmbedding, MFMA version (fp32 I/O, bf16 fragments, fp32 acc)
// Folds: K-proj into score vectors (then through conv -> cwq),
//        V+out proj into M matrices, embed into xbar-GEMM via weighted pixels.
// R3->R4 fix: C3 wsum read outg2 columns (ec&15)*8 (both heads read the same
// 128-dim out row; head concat lives in MeB's K-dim) — was overrunning rows.
// ---------------------------------------------------------------------------

typedef __attribute__((ext_vector_type(8))) short short8;
typedef __attribute__((ext_vector_type(4))) float f32x4;

#define NG 12

__constant__ int GOFF[13] = {0,7,14,21,28,35,44,53,62,71,80,97,103};
__constant__ int GKT[12]  = {2,2,2,2,2,2,2,2,2,2,3,1};
__constant__ int GOFFB[12]= {0,2,4,6,8,10,12,14,16,18,20,23};
__constant__ int KSLOT_GI[24] = {0,0,1,1,2,2,3,3,4,4,5,5,6,6,7,7,8,8,9,9,10,10,10,11};
__constant__ int GSLOT[103] = {
  3,8,13,18,23,28,33,
  4,9,14,19,24,29,34,
  2,7,12,17,22,27,32,
  1,6,11,16,21,26,31,
  0,5,10,15,20,25,30,
  3,8,13,18,23,28,33,38,43,
  4,9,14,19,24,29,34,39,44,
  2,7,12,17,22,27,32,37,42,
  1,6,11,16,21,26,31,36,41,
  0,5,10,15,20,25,30,35,40,
  45,46,47,48,49,50,51,52,53,54,55,56,57,58,59,60,61,
  62,63,64,65,66,67};
__constant__ int GIDX[103] = {
  0,0,0,0,0,0,0, 1,1,1,1,1,1,1, 2,2,2,2,2,2,2, 3,3,3,3,3,3,3, 4,4,4,4,4,4,4,
  5,5,5,5,5,5,5,5,5, 6,6,6,6,6,6,6,6,6, 7,7,7,7,7,7,7,7,7, 8,8,8,8,8,8,8,8,8,
  9,9,9,9,9,9,9,9,9,
  10,10,10,10,10,10,10,10,10,10,10,10,10,10,10,10,10,
  11,11,11,11,11,11};

// fp32 workspace region (float offsets)
#define QK_GRP 0        // [12][2][128]
#define QK_ENS 3072     // [12][2][128]  ((t*2+h)*128+e)
#define QB_GRP 6144     // [12][2]
#define QB_ENS 6176     // [24]
#define CGRP   6208     // [12][128]
#define CENS   7744     // [128]
#define QF_GRP 7872     // [12][128]
#define QF_ENS 9408     // [12][128]
// byte offsets in d_ws
#define CWQ_BYTE   43776   // float [103][2][8]  (cwq*0.125, [4]=cbq*0.125)
#define MGB_BYTE   50432   // ushort [12][8mt][8kt][64][8]
#define MEB_BYTE   836864  // ushort [8mt][8kt][64][8]
#define CW2B_BYTE  902400  // ushort [24kslot][8nt][64][8]
#define QKEB_BYTE  1099008 // ushort [2nt][4kt][64][8]

__device__ __forceinline__ float bf2f(unsigned short s) {
  return __uint_as_float(((unsigned)s) << 16);
}
__device__ __forceinline__ unsigned short f2bf(float f) {
  unsigned u = __float_as_uint(f);
  u += 0x7fffu + ((u >> 16) & 1u);
  return (unsigned short)(u >> 16);
}

// ---------------------------------------------------------------------------
// pre1: q_full + folded bias vectors
// ---------------------------------------------------------------------------
__global__ void hwe_pre1(const float* __restrict__ giw, const float* __restrict__ gib,
                         const float* __restrict__ gow, const float* __restrict__ gob,
                         const float* __restrict__ cq,  const float* __restrict__ eq,
                         const float* __restrict__ eiw, const float* __restrict__ eib,
                         const float* __restrict__ eow, const float* __restrict__ eob,
                         float* __restrict__ wsf) {
  int blk = blockIdx.x, d = threadIdx.x;
  if (blk < 12) {
    int i = blk;
    float acc = gib[i*384 + d];
    for (int e = 0; e < 128; ++e) acc += giw[i*49152 + d*128 + e] * cq[i*128 + e];
    wsf[QF_GRP + i*128 + d] = acc;
  } else if (blk < 24) {
    int i = blk - 12;
    float acc = gob[i*128 + d];
    for (int k = 0; k < 128; ++k) acc += gow[i*16384 + d*128 + k] * gib[i*384 + 256 + k];
    wsf[CGRP + i*128 + d] = acc;
  } else if (blk < 36) {
    int t = blk - 24;
    float acc = eib[d];
    for (int e = 0; e < 128; ++e) acc += eiw[d*128 + e] * eq[t*128 + e];
    wsf[QF_ENS + t*128 + d] = acc;
  } else {
    float acc = eob[d];
    for (int k = 0; k < 128; ++k) acc += eow[d*128 + k] * eib[256 + k];
    wsf[CENS + d] = acc;
  }
}

// ---------------------------------------------------------------------------
// pre2: qk = Wk^T q per head, qb = q.bk
// ---------------------------------------------------------------------------
__global__ void hwe_pre2(const float* __restrict__ giw, const float* __restrict__ gib,
                         const float* __restrict__ eiw, const float* __restrict__ eib,
                         float* __restrict__ wsf) {
  int blk = blockIdx.x, e = threadIdx.x;
  if (blk < 24) {
    int i = blk >> 1, h = blk & 1;
    float acc = 0.f;
    for (int dp = 0; dp < 64; ++dp)
      acc += wsf[QF_GRP + i*128 + h*64 + dp] * giw[i*49152 + (128 + h*64 + dp)*128 + e];
    wsf[QK_GRP + (i*2 + h)*128 + e] = acc;
    if (e == 0) {
      float ab = 0.f;
      for (int dp = 0; dp < 64; ++dp)
        ab += wsf[QF_GRP + i*128 + h*64 + dp] * gib[i*384 + 128 + h*64 + dp];
      wsf[QB_GRP + i*2 + h] = ab;
    }
  } else {
    int tb = blk - 24, t = tb >> 1, h = tb & 1;
    float acc = 0.f;
    for (int dp = 0; dp < 64; ++dp)
      acc += wsf[QF_ENS + t*128 + h*64 + dp] * eiw[(128 + h*64 + dp)*128 + e];
    wsf[QK_ENS + (t*2 + h)*128 + e] = acc;
    if (e == 0) {
      float ab = 0.f;
      for (int dp = 0; dp < 64; ++dp)
        ab += wsf[QF_ENS + t*128 + h*64 + dp] * eib[128 + h*64 + dp];
      wsf[QB_ENS + t*2 + h] = ab;
    }
  }
}

// ---------------------------------------------------------------------------
// pre2b: cwq[gg][h][pp] = 0.125 * qk_h . cw[v][pp][:]; [4] = 0.125*(qk.(cb+ce)+qb)
// ---------------------------------------------------------------------------
__global__ void hwe_pre2b(const float* __restrict__ cw, const float* __restrict__ cb,
                          const float* __restrict__ ce, const float* __restrict__ wsf,
                          float* __restrict__ cwq) {
  int tid = threadIdx.x;
  if (tid >= 206) return;
  int gg = tid >> 1, h = tid & 1;
  int gi = GIDX[gg];
  int s = GSLOT[gg];
  int v = (s < 45) ? s : s + 20;
  const float* qk = wsf + QK_GRP + (gi*2 + h)*128;
  float a0=0.f, a1=0.f, a2=0.f, a3=0.f, ab=0.f;
  for (int e = 0; e < 128; ++e) {
    float q = qk[e];
    a0 += cw[(v*4 + 0)*128 + e] * q;
    a1 += cw[(v*4 + 1)*128 + e] * q;
    a2 += cw[(v*4 + 2)*128 + e] * q;
    a3 += cw[(v*4 + 3)*128 + e] * q;
    ab += (cb[v*128 + e] + ce[v*128 + e]) * q;
  }
  float* o = cwq + (gg*2 + h)*8;
  o[0] = a0*0.125f; o[1] = a1*0.125f; o[2] = a2*0.125f; o[3] = a3*0.125f;
  o[4] = (ab + wsf[QB_GRP + gi*2 + h]) * 0.125f;
}

// ---------------------------------------------------------------------------
// pre3: fragment-swizzled tables MgB, MeB, cw2B, qkeB
// A-frag: value(m=lane&15, k=quad*8+j); B-frag: value(k=quad*8+j, n=lane&15)
// ---------------------------------------------------------------------------
__global__ void hwe_pre3(const float* __restrict__ giw, const float* __restrict__ gow,
                         const float* __restrict__ eiw, const float* __restrict__ eow,
                         const float* __restrict__ cw,  const float* __restrict__ cb,
                         const float* __restrict__ ce,  const float* __restrict__ wsf,
                         unsigned short* __restrict__ MgB, unsigned short* __restrict__ MeB,
                         unsigned short* __restrict__ cw2B, unsigned short* __restrict__ qkeB) {
  int blk = blockIdx.x, tid = threadIdx.x;
  int flat = blk*256 + tid;
  if (blk < 1536) {                 // MgB: M_h[r][e] = sum_hd Wout[r][h64+hd]*Wv[h64+hd][e]
    int gi = flat >> 15;
    int rem = flat & 32767;
    int r = rem >> 8, ep = rem & 255;
    int h = ep >> 7, e = ep & 127;
    float acc = 0.f;
    for (int hd = 0; hd < 64; ++hd)
      acc += gow[gi*16384 + r*128 + h*64 + hd] * giw[gi*49152 + (256 + h*64 + hd)*128 + e];
    int mt = r >> 4, lr = r & 15, kt = ep >> 5, q = (ep >> 3) & 3, j = ep & 7;
    MgB[(((gi*8 + mt)*8 + kt)*64 + (q*16 + lr))*8 + j] = f2bf(acc);
  } else if (blk < 1664) {          // MeB
    int f2 = flat - 1536*256;
    int r = f2 >> 8, ep = f2 & 255;
    int h = ep >> 7, e = ep & 127;
    float acc = 0.f;
    for (int hd = 0; hd < 64; ++hd)
      acc += eow[r*128 + h*64 + hd] * eiw[(256 + h*64 + hd)*128 + e];
    int mt = r >> 4, lr = r & 15, kt = ep >> 5, q = (ep >> 3) & 3, j = ep & 7;
    MeB[((mt*8 + kt)*64 + (q*16 + lr))*8 + j] = f2bf(acc);
  } else if (blk < 2048) {          // cw2B: B[k=(g,pp)][e], pp==4 -> conv_b+chem
    int f3 = flat - 1664*256;       // [0, 98304)
    int kslot = f3 >> 12;
    int lane = (f3 >> 3) & 63, j = f3 & 7;
    int nt = (f3 >> 9) & 7;
    int gi = KSLOT_GI[kslot];
    int kt = kslot - GOFFB[gi];
    int k = kt*32 + (lane >> 4)*8 + j;
    int e = nt*16 + (lane & 15);
    int go = GOFF[gi], G = GOFF[gi+1] - go;
    float val = 0.f;
    if (k < 5*G) {
      int gg = go + k/5, pp = k - (k/5)*5;
      int s = GSLOT[gg];
      int v = (s < 45) ? s : s + 20;
      val = (pp < 4) ? cw[(v*4 + pp)*128 + e] : (cb[v*128 + e] + ce[v*128 + e]);
    }
    cw2B[f3] = f2bf(val);
  } else {                          // qkeB: B[k=r][n=th]
    int f4 = flat - 2048*256;       // [0,4096)
    int lane = (f4 >> 3) & 63, j = f4 & 7;
    int th = ((f4 >> 11) & 1)*16 + (lane & 15);
    int kt = (f4 >> 9) & 3;
    float val = (th < 24) ? wsf[QK_ENS + th*128 + kt*32 + (lane >> 4)*8 + j] : 0.f;
    qkeB[f4] = f2bf(val);
  }
}

// ---------------------------------------------------------------------------
// Main kernel. grid 1024, block 256 (4 waves). 8 patches per block.
// LDS layout (bytes), total 51744:
//   0      xpB  ushort [8p][68s][4pp]   4352   (phase A/B)  | rObuf f32 [12][132] (C)
//   4352   scb  ushort [8p][2h][104]    3328   (A/B)
//   7680   wpA  ushort [16][104]        3328   (B)
//   11008  XBt  ushort [16][264]        8448   (B)          | XEt (C)
//   19456  outg2 ushort [96][136]       26112  (B writes, C reads)
//   45568  sce2 ushort [192][16]        6144   (C)
//   51712  stats float [8]              32
// ---------------------------------------------------------------------------
__global__ __launch_bounds__(256, 3) void hwe_main(
    const float* __restrict__ x,
    const float* __restrict__ lgam, const float* __restrict__ lbet,
    const float* __restrict__ wsf,  const float* __restrict__ cwq,
    const unsigned short* __restrict__ MgB, const unsigned short* __restrict__ MeB,
    const unsigned short* __restrict__ cw2B, const unsigned short* __restrict__ qkeB,
    float* __restrict__ out) {
  __shared__ __align__(16) unsigned char smem[51744];
  unsigned short* xpB   = (unsigned short*)(smem);
  unsigned short* scb   = (unsigned short*)(smem + 4352);
  unsigned short* wpA   = (unsigned short*)(smem + 7680);
  unsigned short* XBt   = (unsigned short*)(smem + 11008);
  unsigned short* XEt   = XBt;
  float*          rObuf = (float*)(smem);
  unsigned short* outg2 = (unsigned short*)(smem + 19456);
  unsigned short* sce2  = (unsigned short*)(smem + 45568);
  float*          stats = (float*)(smem + 51712);

  const int tid  = threadIdx.x;
  const int wave = tid >> 6;
  const int lane = tid & 63;
  const int quad = lane >> 4;
  const int l15  = lane & 15;

  const int hi   = blockIdx.x >> 4;
  const int wib  = (blockIdx.x & 15) << 3;
  const int nbase = hi*128 + wib;

  // ---- A1: raw 2x2 pixels for 8 patches, 68 used channels ----
  for (int idx = tid; idx < 2176; idx += 256) {
    int c = idx & 15, r = (idx >> 4) & 1, s = idx >> 5;
    int v = (s < 45) ? s : s + 20;
    float val = x[(v*128 + 2*hi + r)*256 + 2*wib + c];
    int p = c >> 1, pp = r*2 + (c & 1);
    xpB[(p*68 + s)*4 + pp] = f2bf(val);
  }
  __syncthreads();

  // ---- A2: all group scores via cwq fold (pre-scaled) ----
  for (int idx = tid; idx < 1648; idx += 256) {
    int h = idx & 1, p = (idx >> 1) & 7, gg = idx >> 4;
    int s = GSLOT[gg];
    const float* c = cwq + (gg*2 + h)*8;
    const unsigned short* xr = xpB + (p*68 + s)*4;
    float acc = c[4] + bf2f(xr[0])*c[0] + bf2f(xr[1])*c[1]
                     + bf2f(xr[2])*c[2] + bf2f(xr[3])*c[3];
    scb[(p*2 + h)*104 + gg] = f2bf(acc);
  }
  __syncthreads();

  // ---- A3: softmax per (p,h,group) ----
  if (tid < 192) {
    int gi = tid % 12, h = (tid / 12) & 1, p = tid / 24;
    int go = GOFF[gi], G = GOFF[gi+1] - go;
    unsigned short* row = scb + (p*2 + h)*104 + go;
    float m = -1e30f;
    for (int g = 0; g < G; ++g) m = fmaxf(m, bf2f(row[g]));
    float ssum = 0.f;
    for (int g = 0; g < G; ++g) {
      float ev = __expf(bf2f(row[g]) - m);
      ssum += ev;
      row[g] = f2bf(ev);
    }
    float inv = 1.f / ssum;
    for (int g = 0; g < G; ++g) row[g] = f2bf(bf2f(row[g]) * inv);
  }
  __syncthreads();

  // ---- Phase B: per group — weighted pixels -> xbar GEMM -> matvec GEMM ----
  for (int gi = 0; gi < NG; ++gi) {
    const int go = GOFF[gi], G = GOFF[gi+1] - go;
    const int KT = GKT[gi], gb = GOFFB[gi];
    const int K5 = 5*G;

    // B1: wpA[row=(h*8+p)][k=(g,pp)] = a*pixel (pp<4) or a (pp==4)
    for (int idx = tid; idx < 1536; idx += 256) {
      int row = idx / 96, k = idx - (idx / 96)*96;
      int h = row >> 3, p = row & 7;
      float val = 0.f;
      if (k < K5) {
        int gg = go + k/5, pp = k - (k/5)*5;
        float a = bf2f(scb[(p*2 + h)*104 + gg]);
        val = (pp < 4) ? a * bf2f(xpB[(p*68 + GSLOT[gg])*4 + pp]) : a;
      }
      wpA[row*104 + k] = f2bf(val);
    }
    __syncthreads();

    // B2: xbar GEMM (M=16 rows (h,p), N=128 e, K=KT*32) -> XBt[p][h*128+e]
    for (int nti = 0; nti < 2; ++nti) {
      int nt = wave*2 + nti;
      f32x4 acc = {0.f, 0.f, 0.f, 0.f};
      for (int kt = 0; kt < KT; ++kt) {
        short8 a = *(const short8*)(wpA + l15*104 + kt*32 + quad*8);
        short8 b = *(const short8*)(cw2B + (((gb + kt)*8 + nt)*64 + lane)*8);
        acc = __builtin_amdgcn_mfma_f32_16x16x32_bf16(a, b, acc, 0, 0, 0);
      }
      int e = nt*16 + l15;
#pragma unroll
      for (int reg = 0; reg < 4; ++reg) {
        int rr = quad*4 + reg;
        XBt[(rr & 7)*264 + (rr >> 3)*128 + e] = f2bf(acc[reg]);
      }
    }
    __syncthreads();

    // B3: matvec GEMM (M=128 r, N=8 p, K=256 e') -> outg2[(gi*8+p)][r]
    {
      f32x4 acc0 = {0.f,0.f,0.f,0.f}, acc1 = {0.f,0.f,0.f,0.f};
      int mtA = wave*2, mtB = wave*2 + 1;
#pragma unroll
      for (int kt = 0; kt < 8; ++kt) {
        short8 b  = *(const short8*)(XBt + l15*264 + kt*32 + quad*8);
        short8 a0 = *(const short8*)(MgB + (((gi*8 + mtA)*8 + kt)*64 + lane)*8);
        short8 a1 = *(const short8*)(MgB + (((gi*8 + mtB)*8 + kt)*64 + lane)*8);
        acc0 = __builtin_amdgcn_mfma_f32_16x16x32_bf16(a0, b, acc0, 0, 0, 0);
        acc1 = __builtin_amdgcn_mfma_f32_16x16x32_bf16(a1, b, acc1, 0, 0, 0);
      }
      if (l15 < 8) {
        int p = l15;
#pragma unroll
        for (int mi = 0; mi < 2; ++mi) {
          int mt = wave*2 + mi;
          f32x4 acc = mi ? acc1 : acc0;
          unsigned short t0 = f2bf(acc[0] + wsf[CGRP + gi*128 + mt*16 + quad*4 + 0]);
          unsigned short t1 = f2bf(acc[1] + wsf[CGRP + gi*128 + mt*16 + quad*4 + 1]);
          unsigned short t2 = f2bf(acc[2] + wsf[CGRP + gi*128 + mt*16 + quad*4 + 2]);
          unsigned short t3 = f2bf(acc[3] + wsf[CGRP + gi*128 + mt*16 + quad*4 + 3]);
          uint2 w;
          w.x = (unsigned)t0 | ((unsigned)t1 << 16);
          w.y = (unsigned)t2 | ((unsigned)t3 << 16);
          *(uint2*)(outg2 + (gi*8 + p)*136 + mt*16 + quad*4) = w;
        }
      }
    }
    __syncthreads();
  }

  // ---- Phase C ----
  // Preload ensemble M fragments into registers (reused for all 8 patches)
  short8 meA[2][8];
#pragma unroll
  for (int mi = 0; mi < 2; ++mi)
#pragma unroll
    for (int kt = 0; kt < 8; ++kt)
      meA[mi][kt] = *(const short8*)(MeB + (((wave*2 + mi)*8 + kt)*64 + lane)*8);

  // C1: ens scores GEMM (M=96 rows (s,p), N=24 (t,h), K=128 r)
  for (int ti = 0; ti < 3; ++ti) {
    int T = wave*3 + ti;
    int mtp = T >> 1, ntp = T & 1;
    f32x4 acc = {0.f,0.f,0.f,0.f};
#pragma unroll
    for (int kt = 0; kt < 4; ++kt) {
      short8 a = *(const short8*)(outg2 + (mtp*16 + l15)*136 + kt*32 + quad*8);
      short8 b = *(const short8*)(qkeB + ((ntp*4 + kt)*64 + lane)*8);
      acc = __builtin_amdgcn_mfma_f32_16x16x32_bf16(a, b, acc, 0, 0, 0);
    }
    int th = ntp*16 + l15;
    if (th < 24) {
      float qb = wsf[QB_ENS + th];
#pragma unroll
      for (int reg = 0; reg < 4; ++reg) {
        int rowE = mtp*16 + quad*4 + reg;
        sce2[((rowE & 7)*24 + th)*16 + (rowE >> 3)] = f2bf((acc[reg] + qb) * 0.125f);
      }
    }
  }
  __syncthreads();

  // C2: softmax over s per (p, t, h)
  if (tid < 192) {
    unsigned short* row = sce2 + tid*16;
    float m = -1e30f;
    for (int s = 0; s < 12; ++s) m = fmaxf(m, bf2f(row[s]));
    float ssum = 0.f;
    for (int s = 0; s < 12; ++s) {
      float ev = __expf(bf2f(row[s]) - m);
      ssum += ev;
      row[s] = f2bf(ev);
    }
    float inv = 1.f / ssum;
    for (int s = 0; s < 12; ++s) row[s] = f2bf(bf2f(row[s]) * inv);
  }
  __syncthreads();

  // C3: per patch: weighted sum -> ens matvec GEMM -> LayerNorm
  for (int p = 0; p < 8; ++p) {
    // wsum: XEt[t][e'=h*128+e] = sum_s a[p,h,t,s] * outg2[(s,p)][e]
    // (both heads read the SAME 128-dim out row; h only selects the a-row)
    for (int idx = tid; idx < 384; idx += 256) {
      int t = idx >> 5, ec = idx & 31, h = ec >> 4;
      int ecr = ec & 15;  // column block within the 128-dim out row
      const unsigned short* arow = sce2 + (p*24 + t*2 + h)*16;
      float a0=0.f,a1=0.f,a2=0.f,a3=0.f,a4=0.f,a5=0.f,a6=0.f,a7=0.f;
      for (int s = 0; s < 12; ++s) {
        float av = bf2f(arow[s]);
        uint4 o = *(const uint4*)(outg2 + (s*8 + p)*136 + ecr*8);
        a0 += av * __uint_as_float(o.x << 16);
        a1 += av * __uint_as_float(o.x & 0xffff0000u);
        a2 += av * __uint_as_float(o.y << 16);
        a3 += av * __uint_as_float(o.y & 0xffff0000u);
        a4 += av * __uint_as_float(o.z << 16);
        a5 += av * __uint_as_float(o.z & 0xffff0000u);
        a6 += av * __uint_as_float(o.w << 16);
        a7 += av * __uint_as_float(o.w & 0xffff0000u);
      }
      uint4 w;
      w.x = (unsigned)f2bf(a0) | ((unsigned)f2bf(a1) << 16);
      w.y = (unsigned)f2bf(a2) | ((unsigned)f2bf(a3) << 16);
      w.z = (unsigned)f2bf(a4) | ((unsigned)f2bf(a5) << 16);
      w.w = (unsigned)f2bf(a6) | ((unsigned)f2bf(a7) << 16);
      *(uint4*)(XEt + t*264 + ec*8) = w;
    }
    __syncthreads();

    // ens matvec: R[r][t] = Mcat_e @ XEt^T, + cens -> rObuf[t][r]
    {
      f32x4 acc0 = {0.f,0.f,0.f,0.f}, acc1 = {0.f,0.f,0.f,0.f};
#pragma unroll
      for (int kt = 0; kt < 8; ++kt) {
        short8 b = *(const short8*)(XEt + l15*264 + kt*32 + quad*8);
        acc0 = __builtin_amdgcn_mfma_f32_16x16x32_bf16(meA[0][kt], b, acc0, 0, 0, 0);
        acc1 = __builtin_amdgcn_mfma_f32_16x16x32_bf16(meA[1][kt], b, acc1, 0, 0, 0);
      }
      if (l15 < 12) {
        int t = l15;
#pragma unroll
        for (int mi = 0; mi < 2; ++mi) {
          int rb = (wave*2 + mi)*16 + quad*4;
          f32x4 acc = mi ? acc1 : acc0;
          f32x4 v;
          v[0] = acc[0] + wsf[CENS + rb + 0];
          v[1] = acc[1] + wsf[CENS + rb + 1];
          v[2] = acc[2] + wsf[CENS + rb + 2];
          v[3] = acc[3] + wsf[CENS + rb + 3];
          *(f32x4*)(rObuf + t*132 + rb) = v;
        }
      }
    }
    __syncthreads();

    // LayerNorm over 1536
    float s1 = 0.f, s2 = 0.f;
#pragma unroll
    for (int it = 0; it < 6; ++it) {
      int j = tid + it*256;
      float v = rObuf[(j >> 7)*132 + (j & 127)];
      s1 += v; s2 += v*v;
    }
#pragma unroll
    for (int off = 32; off > 0; off >>= 1) {
      s1 += __shfl_down(s1, off);
      s2 += __shfl_down(s2, off);
    }
    if (lane == 0) { stats[wave*2] = s1; stats[wave*2 + 1] = s2; }
    __syncthreads();
    float t1 = stats[0] + stats[2] + stats[4] + stats[6];
    float t2 = stats[1] + stats[3] + stats[5] + stats[7];
    float mean = t1 * (1.f/1536.f);
    float var  = t2 * (1.f/1536.f) - mean*mean;
    float rstd = rsqrtf(var + 1e-5f);
    long nrow = (long)(nbase + p) * 1536;
#pragma unroll
    for (int it = 0; it < 6; ++it) {
      int j = tid + it*256;
      float v = rObuf[(j >> 7)*132 + (j & 127)];
      out[nrow + j] = (v - mean) * rstd * lgam[j] + lbet[j];
    }
    __syncthreads();
  }
}

// ---------------------------------------------------------------------------
extern "C" void kernel_launch(void* const* d_in, const int* in_sizes, int n_in,
                              void* d_out, int out_size, void* d_ws, size_t ws_size,
                              hipStream_t stream) {
  const float* x   = (const float*)d_in[0];
  const float* cw  = (const float*)d_in[1];
  const float* cb  = (const float*)d_in[2];
  const float* ce  = (const float*)d_in[3];
  const float* cq  = (const float*)d_in[4];
  const float* giw = (const float*)d_in[5];
  const float* gib = (const float*)d_in[6];
  const float* gow = (const float*)d_in[7];
  const float* gob = (const float*)d_in[8];
  const float* eq  = (const float*)d_in[9];
  const float* eiw = (const float*)d_in[10];
  const float* eib = (const float*)d_in[11];
  const float* eow = (const float*)d_in[12];
  const float* eob = (const float*)d_in[13];
  const float* lg  = (const float*)d_in[14];
  const float* lb  = (const float*)d_in[15];

  float* wsf = (float*)d_ws;
  float* cwq = (float*)((char*)d_ws + CWQ_BYTE);
  unsigned short* MgB  = (unsigned short*)((char*)d_ws + MGB_BYTE);
  unsigned short* MeB  = (unsigned short*)((char*)d_ws + MEB_BYTE);
  unsigned short* cw2B = (unsigned short*)((char*)d_ws + CW2B_BYTE);
  unsigned short* qkeB = (unsigned short*)((char*)d_ws + QKEB_BYTE);

  hwe_pre1<<<37, 128, 0, stream>>>(giw, gib, gow, gob, cq, eq, eiw, eib, eow, eob, wsf);
  hwe_pre2<<<48, 128, 0, stream>>>(giw, gib, eiw, eib, wsf);
  hwe_pre2b<<<1, 256, 0, stream>>>(cw, cb, ce, wsf, cwq);
  hwe_pre3<<<2064, 256, 0, stream>>>(giw, gow, eiw, eow, cw, cb, ce, wsf,
                                     MgB, MeB, cw2B, qkeB);
  hwe_main<<<1024, 256, 0, stream>>>(x, lg, lb, wsf, cwq,
                                     MgB, MeB, cw2B, qkeB, (float*)d_out);
}

// Round 5
// 291.597 us; speedup vs baseline: 2.5537x; 1.0465x over previous
//
#include <hip/hip_runtime.h>

// ---------------------------------------------------------------------------
// HieraWeatherEmbedding, MFMA version (fp32 I/O, bf16 fragments, fp32 acc)
// R4->R5: barrier reduction. Phase B: 2 groups per barrier period (wave-pair
// per group). Phase C: 4 patches per period, batched N=48 ens-matvec GEMM,
// wave-per-patch LayerNorm. Pre-chain: pre1 -> wave-per-output coalesced;
// pre2b folded into pre3.
// ---------------------------------------------------------------------------

typedef __attribute__((ext_vector_type(8))) short short8;
typedef __attribute__((ext_vector_type(4))) float f32x4;

#define NG 12

__constant__ int GOFF[13] = {0,7,14,21,28,35,44,53,62,71,80,97,103};
__constant__ int GKT[12]  = {2,2,2,2,2,2,2,2,2,2,3,1};
__constant__ int GOFFB[12]= {0,2,4,6,8,10,12,14,16,18,20,23};
__constant__ int KSLOT_GI[24] = {0,0,1,1,2,2,3,3,4,4,5,5,6,6,7,7,8,8,9,9,10,10,10,11};
__constant__ int GSLOT[103] = {
  3,8,13,18,23,28,33,
  4,9,14,19,24,29,34,
  2,7,12,17,22,27,32,
  1,6,11,16,21,26,31,
  0,5,10,15,20,25,30,
  3,8,13,18,23,28,33,38,43,
  4,9,14,19,24,29,34,39,44,
  2,7,12,17,22,27,32,37,42,
  1,6,11,16,21,26,31,36,41,
  0,5,10,15,20,25,30,35,40,
  45,46,47,48,49,50,51,52,53,54,55,56,57,58,59,60,61,
  62,63,64,65,66,67};
__constant__ int GIDX[103] = {
  0,0,0,0,0,0,0, 1,1,1,1,1,1,1, 2,2,2,2,2,2,2, 3,3,3,3,3,3,3, 4,4,4,4,4,4,4,
  5,5,5,5,5,5,5,5,5, 6,6,6,6,6,6,6,6,6, 7,7,7,7,7,7,7,7,7, 8,8,8,8,8,8,8,8,8,
  9,9,9,9,9,9,9,9,9,
  10,10,10,10,10,10,10,10,10,10,10,10,10,10,10,10,10,
  11,11,11,11,11,11};

// fp32 workspace region (float offsets)
#define QK_GRP 0        // [12][2][128]
#define QK_ENS 3072     // [12][2][128]  ((t*2+h)*128+e)
#define QB_GRP 6144     // [12][2]
#define QB_ENS 6176     // [24]
#define CGRP   6208     // [12][128]
#define CENS   7744     // [128]
#define QF_GRP 7872     // [12][128]
#define QF_ENS 9408     // [12][128]
// byte offsets in d_ws
#define CWQ_BYTE   43776   // float [103][2][8]  (cwq*0.125, [4]=cbq*0.125)
#define MGB_BYTE   50432   // ushort [12][8mt][8kt][64][8]
#define MEB_BYTE   836864  // ushort [8mt][8kt][64][8]
#define CW2B_BYTE  902400  // ushort [24kslot][8nt][64][8]
#define QKEB_BYTE  1099008 // ushort [2nt][4kt][64][8]

__device__ __forceinline__ float bf2f(unsigned short s) {
  return __uint_as_float(((unsigned)s) << 16);
}
__device__ __forceinline__ unsigned short f2bf(float f) {
  unsigned u = __float_as_uint(f);
  u += 0x7fffu + ((u >> 16) & 1u);
  return (unsigned short)(u >> 16);
}

// ---------------------------------------------------------------------------
// preA: q_full + folded bias vectors — wave per output, lane over K (coalesced)
// 4736 outputs = 1184 blocks * 4 waves
// ---------------------------------------------------------------------------
__global__ void hwe_preA(const float* __restrict__ giw, const float* __restrict__ gib,
                         const float* __restrict__ gow, const float* __restrict__ gob,
                         const float* __restrict__ cq,  const float* __restrict__ eq,
                         const float* __restrict__ eiw, const float* __restrict__ eib,
                         const float* __restrict__ eow, const float* __restrict__ eob,
                         float* __restrict__ wsf) {
  int id = blockIdx.x*4 + (threadIdx.x >> 6);
  int lane = threadIdx.x & 63;
  float acc, bias;
  int dst;
  if (id < 1536) {                       // QF_GRP
    int i = id >> 7, d = id & 127;
    const float* wrow = giw + i*49152 + d*128;
    const float* qv = cq + i*128;
    acc = wrow[lane]*qv[lane] + wrow[lane+64]*qv[lane+64];
    bias = gib[i*384 + d];
    dst = QF_GRP + id;
  } else if (id < 3072) {                // CGRP
    int r = id - 1536; int i = r >> 7, d = r & 127;
    const float* wrow = gow + i*16384 + d*128;
    const float* bv = gib + i*384 + 256;
    acc = wrow[lane]*bv[lane] + wrow[lane+64]*bv[lane+64];
    bias = gob[i*128 + d];
    dst = CGRP + r;
  } else if (id < 4608) {                // QF_ENS
    int r = id - 3072; int t = r >> 7, d = r & 127;
    const float* wrow = eiw + d*128;
    const float* qv = eq + t*128;
    acc = wrow[lane]*qv[lane] + wrow[lane+64]*qv[lane+64];
    bias = eib[d];
    dst = QF_ENS + r;
  } else {                               // CENS
    int d = id - 4608;
    const float* wrow = eow + d*128;
    const float* bv = eib + 256;
    acc = wrow[lane]*bv[lane] + wrow[lane+64]*bv[lane+64];
    bias = eob[d];
    dst = CENS + d;
  }
#pragma unroll
  for (int off = 32; off > 0; off >>= 1) acc += __shfl_down(acc, off);
  if (lane == 0) wsf[dst] = acc + bias;
}

// ---------------------------------------------------------------------------
// pre2: qk = Wk^T q per head, qb = q.bk (lanes over e, coalesced; 64 iters)
// ---------------------------------------------------------------------------
__global__ void hwe_pre2(const float* __restrict__ giw, const float* __restrict__ gib,
                         const float* __restrict__ eiw, const float* __restrict__ eib,
                         float* __restrict__ wsf) {
  int blk = blockIdx.x, e = threadIdx.x;
  if (blk < 24) {
    int i = blk >> 1, h = blk & 1;
    float acc = 0.f;
    for (int dp = 0; dp < 64; ++dp)
      acc += wsf[QF_GRP + i*128 + h*64 + dp] * giw[i*49152 + (128 + h*64 + dp)*128 + e];
    wsf[QK_GRP + (i*2 + h)*128 + e] = acc;
    if (e == 0) {
      float ab = 0.f;
      for (int dp = 0; dp < 64; ++dp)
        ab += wsf[QF_GRP + i*128 + h*64 + dp] * gib[i*384 + 128 + h*64 + dp];
      wsf[QB_GRP + i*2 + h] = ab;
    }
  } else {
    int tb = blk - 24, t = tb >> 1, h = tb & 1;
    float acc = 0.f;
    for (int dp = 0; dp < 64; ++dp)
      acc += wsf[QF_ENS + t*128 + h*64 + dp] * eiw[(128 + h*64 + dp)*128 + e];
    wsf[QK_ENS + (t*2 + h)*128 + e] = acc;
    if (e == 0) {
      float ab = 0.f;
      for (int dp = 0; dp < 64; ++dp)
        ab += wsf[QF_ENS + t*128 + h*64 + dp] * eib[128 + h*64 + dp];
      wsf[QB_ENS + t*2 + h] = ab;
    }
  }
}

// ---------------------------------------------------------------------------
// pre3: fragment tables MgB, MeB, cw2B, qkeB + cwq (wave-per-output section)
// A-frag: value(m=lane&15, k=quad*8+j); B-frag: value(k=quad*8+j, n=lane&15)
// ---------------------------------------------------------------------------
__global__ void hwe_pre3(const float* __restrict__ giw, const float* __restrict__ gow,
                         const float* __restrict__ eiw, const float* __restrict__ eow,
                         const float* __restrict__ cw,  const float* __restrict__ cb,
                         const float* __restrict__ ce,  const float* __restrict__ wsf,
                         unsigned short* __restrict__ MgB, unsigned short* __restrict__ MeB,
                         unsigned short* __restrict__ cw2B, unsigned short* __restrict__ qkeB,
                         float* __restrict__ cwq) {
  int blk = blockIdx.x, tid = threadIdx.x;
  int flat = blk*256 + tid;
  if (blk < 1536) {                 // MgB
    int gi = flat >> 15;
    int rem = flat & 32767;
    int r = rem >> 8, ep = rem & 255;
    int h = ep >> 7, e = ep & 127;
    float acc = 0.f;
    for (int hd = 0; hd < 64; ++hd)
      acc += gow[gi*16384 + r*128 + h*64 + hd] * giw[gi*49152 + (256 + h*64 + hd)*128 + e];
    int mt = r >> 4, lr = r & 15, kt = ep >> 5, q = (ep >> 3) & 3, j = ep & 7;
    MgB[(((gi*8 + mt)*8 + kt)*64 + (q*16 + lr))*8 + j] = f2bf(acc);
  } else if (blk < 1664) {          // MeB
    int f2 = flat - 1536*256;
    int r = f2 >> 8, ep = f2 & 255;
    int h = ep >> 7, e = ep & 127;
    float acc = 0.f;
    for (int hd = 0; hd < 64; ++hd)
      acc += eow[r*128 + h*64 + hd] * eiw[(256 + h*64 + hd)*128 + e];
    int mt = r >> 4, lr = r & 15, kt = ep >> 5, q = (ep >> 3) & 3, j = ep & 7;
    MeB[((mt*8 + kt)*64 + (q*16 + lr))*8 + j] = f2bf(acc);
  } else if (blk < 2048) {          // cw2B
    int f3 = flat - 1664*256;       // [0, 98304)
    int kslot = f3 >> 12;
    int lane = (f3 >> 3) & 63, j = f3 & 7;
    int nt = (f3 >> 9) & 7;
    int gi = KSLOT_GI[kslot];
    int kt = kslot - GOFFB[gi];
    int k = kt*32 + (lane >> 4)*8 + j;
    int e = nt*16 + (lane & 15);
    int go = GOFF[gi], G = GOFF[gi+1] - go;
    float val = 0.f;
    if (k < 5*G) {
      int gg = go + k/5, pp = k - (k/5)*5;
      int s = GSLOT[gg];
      int v = (s < 45) ? s : s + 20;
      val = (pp < 4) ? cw[(v*4 + pp)*128 + e] : (cb[v*128 + e] + ce[v*128 + e]);
    }
    cw2B[f3] = f2bf(val);
  } else if (blk < 2064) {          // qkeB
    int f4 = flat - 2048*256;       // [0,4096)
    int lane = (f4 >> 3) & 63, j = f4 & 7;
    int th = ((f4 >> 11) & 1)*16 + (lane & 15);
    int kt = (f4 >> 9) & 3;
    float val = (th < 24) ? wsf[QK_ENS + th*128 + kt*32 + (lane >> 4)*8 + j] : 0.f;
    qkeB[f4] = f2bf(val);
  } else {                          // cwq: wave per (gg,h), lane over e
    int wid = (blk - 2064)*4 + (tid >> 6);
    int lane = tid & 63;
    if (wid < 206) {
      int gg = wid >> 1, h = wid & 1;
      int gi = GIDX[gg];
      int s = GSLOT[gg];
      int v = (s < 45) ? s : s + 20;
      const float* qk = wsf + QK_GRP + (gi*2 + h)*128;
      float q0 = qk[lane], q1 = qk[lane + 64];
      float a[5];
#pragma unroll
      for (int pp = 0; pp < 4; ++pp)
        a[pp] = cw[(v*4 + pp)*128 + lane]*q0 + cw[(v*4 + pp)*128 + lane + 64]*q1;
      a[4] = (cb[v*128 + lane] + ce[v*128 + lane])*q0 +
             (cb[v*128 + lane + 64] + ce[v*128 + lane + 64])*q1;
#pragma unroll
      for (int off = 32; off > 0; off >>= 1)
#pragma unroll
        for (int kk = 0; kk < 5; ++kk) a[kk] += __shfl_down(a[kk], off);
      if (lane == 0) {
        float* o = cwq + (gg*2 + h)*8;
        o[0] = a[0]*0.125f; o[1] = a[1]*0.125f; o[2] = a[2]*0.125f; o[3] = a[3]*0.125f;
        o[4] = (a[4] + wsf[QB_GRP + gi*2 + h]) * 0.125f;
      }
    }
  }
}

// ---------------------------------------------------------------------------
// Main kernel. grid 1024, block 256 (4 waves). 8 patches per block.
// LDS layout (bytes), total 63488:
//   B-scratch (overlaid by XEt4/rObuf in phase C):
//     0      xpB   ushort [8p][68s][4pp]        4352
//     4352   scb   ushort [8p][2h][104]         3328
//     7680   wpA2  ushort [2][16][104]          6656
//     14336  XBt2  ushort [2][16][264]          16896  -> end 31232
//   C overlay at 0: XEt4 ushort [48][264] 25344; rObuf ushort [48][136] 13056
//   31232  outg2  ushort [96][136]              26112
//   57344  sce2   ushort [192][16]              6144   -> end 63488
// ---------------------------------------------------------------------------
__global__ __launch_bounds__(256, 2) void hwe_main(
    const float* __restrict__ x,
    const float* __restrict__ lgam, const float* __restrict__ lbet,
    const float* __restrict__ wsf,  const float* __restrict__ cwq,
    const unsigned short* __restrict__ MgB, const unsigned short* __restrict__ MeB,
    const unsigned short* __restrict__ cw2B, const unsigned short* __restrict__ qkeB,
    float* __restrict__ out) {
  __shared__ __align__(16) unsigned char smem[63488];
  unsigned short* xpB   = (unsigned short*)(smem);
  unsigned short* scb   = (unsigned short*)(smem + 4352);
  unsigned short* wpA2  = (unsigned short*)(smem + 7680);
  unsigned short* XBt2  = (unsigned short*)(smem + 14336);
  unsigned short* XEt4  = (unsigned short*)(smem);          // C overlay
  unsigned short* rObuf = (unsigned short*)(smem);          // C overlay (post-sync)
  unsigned short* outg2 = (unsigned short*)(smem + 31232);
  unsigned short* sce2  = (unsigned short*)(smem + 57344);

  const int tid  = threadIdx.x;
  const int wave = tid >> 6;
  const int lane = tid & 63;
  const int quad = lane >> 4;
  const int l15  = lane & 15;

  const int hi   = blockIdx.x >> 4;
  const int wib  = (blockIdx.x & 15) << 3;
  const int nbase = hi*128 + wib;

  // ---- A1: raw 2x2 pixels for 8 patches, 68 used channels ----
  for (int idx = tid; idx < 2176; idx += 256) {
    int c = idx & 15, r = (idx >> 4) & 1, s = idx >> 5;
    int v = (s < 45) ? s : s + 20;
    float val = x[(v*128 + 2*hi + r)*256 + 2*wib + c];
    int p = c >> 1, pp = r*2 + (c & 1);
    xpB[(p*68 + s)*4 + pp] = f2bf(val);
  }
  __syncthreads();

  // ---- A2: all group scores via cwq fold (pre-scaled) ----
  for (int idx = tid; idx < 1648; idx += 256) {
    int h = idx & 1, p = (idx >> 1) & 7, gg = idx >> 4;
    int s = GSLOT[gg];
    const float* c = cwq + (gg*2 + h)*8;
    const unsigned short* xr = xpB + (p*68 + s)*4;
    float acc = c[4] + bf2f(xr[0])*c[0] + bf2f(xr[1])*c[1]
                     + bf2f(xr[2])*c[2] + bf2f(xr[3])*c[3];
    scb[(p*2 + h)*104 + gg] = f2bf(acc);
  }
  __syncthreads();

  // ---- A3: softmax per (p,h,group) ----
  if (tid < 192) {
    int gi = tid % 12, h = (tid / 12) & 1, p = tid / 24;
    int go = GOFF[gi], G = GOFF[gi+1] - go;
    unsigned short* row = scb + (p*2 + h)*104 + go;
    float m = -1e30f;
    for (int g = 0; g < G; ++g) m = fmaxf(m, bf2f(row[g]));
    float ssum = 0.f;
    for (int g = 0; g < G; ++g) {
      float ev = __expf(bf2f(row[g]) - m);
      ssum += ev;
      row[g] = f2bf(ev);
    }
    float inv = 1.f / ssum;
    for (int g = 0; g < G; ++g) row[g] = f2bf(bf2f(row[g]) * inv);
  }
  __syncthreads();

  // ---- Phase B: 2 groups per barrier period; wave-pair per group ----
  for (int it = 0; it < 6; ++it) {
    // B1: weighted pixels for both groups
    for (int idx = tid; idx < 3072; idx += 256) {
      int half = (idx >= 1536) ? 1 : 0;
      int rem = idx - half*1536;
      int gi = 2*it + half;
      int go = GOFF[gi];
      int K5 = 5*(GOFF[gi+1] - go);
      int row = rem/96, k = rem - (rem/96)*96;
      int h = row >> 3, p = row & 7;
      float val = 0.f;
      if (k < K5) {
        int gg = go + k/5, pp = k - (k/5)*5;
        float a = bf2f(scb[(p*2 + h)*104 + gg]);
        val = (pp < 4) ? a * bf2f(xpB[(p*68 + GSLOT[gg])*4 + pp]) : a;
      }
      wpA2[half*1664 + row*104 + k] = f2bf(val);
    }
    __syncthreads();

    // B2: xbar GEMM per group (wave-pair): M=16 rows (h,p), N=128, K=KT*32
    {
      int gsel = wave >> 1;
      int gi = 2*it + gsel;
      int KT = GKT[gi], gb = GOFFB[gi];
      unsigned short* wp = wpA2 + gsel*1664;
      unsigned short* xb = XBt2 + gsel*2112;
      for (int nti = 0; nti < 4; ++nti) {
        int nt = (wave & 1)*4 + nti;
        f32x4 acc = {0.f,0.f,0.f,0.f};
        for (int kt = 0; kt < KT; ++kt) {
          short8 a = *(const short8*)(wp + l15*104 + kt*32 + quad*8);
          short8 b = *(const short8*)(cw2B + (((gb + kt)*8 + nt)*64 + lane)*8);
          acc = __builtin_amdgcn_mfma_f32_16x16x32_bf16(a, b, acc, 0, 0, 0);
        }
        int e = nt*16 + l15;
#pragma unroll
        for (int reg = 0; reg < 4; ++reg) {
          int rr = quad*4 + reg;
          xb[(rr & 7)*264 + (rr >> 3)*128 + e] = f2bf(acc[reg]);
        }
      }
    }
    __syncthreads();

    // B3: group matvec GEMM (wave-pair): M=128 r, N=8 p, K=256
    {
      int gsel = wave >> 1;
      int gi = 2*it + gsel;
      unsigned short* xb = XBt2 + gsel*2112;
      f32x4 acc[4] = {{0.f,0.f,0.f,0.f},{0.f,0.f,0.f,0.f},
                      {0.f,0.f,0.f,0.f},{0.f,0.f,0.f,0.f}};
#pragma unroll
      for (int kt = 0; kt < 8; ++kt) {
        short8 b = *(const short8*)(xb + l15*264 + kt*32 + quad*8);
#pragma unroll
        for (int mi = 0; mi < 4; ++mi) {
          int mt = (wave & 1)*4 + mi;
          short8 a = *(const short8*)(MgB + (((gi*8 + mt)*8 + kt)*64 + lane)*8);
          acc[mi] = __builtin_amdgcn_mfma_f32_16x16x32_bf16(a, b, acc[mi], 0, 0, 0);
        }
      }
      if (l15 < 8) {
        int p = l15;
#pragma unroll
        for (int mi = 0; mi < 4; ++mi) {
          int mt = (wave & 1)*4 + mi;
          int rb = gi*128 + mt*16 + quad*4;
          unsigned short t0 = f2bf(acc[mi][0] + wsf[CGRP + rb + 0]);
          unsigned short t1 = f2bf(acc[mi][1] + wsf[CGRP + rb + 1]);
          unsigned short t2 = f2bf(acc[mi][2] + wsf[CGRP + rb + 2]);
          unsigned short t3 = f2bf(acc[mi][3] + wsf[CGRP + rb + 3]);
          uint2 w;
          w.x = (unsigned)t0 | ((unsigned)t1 << 16);
          w.y = (unsigned)t2 | ((unsigned)t3 << 16);
          *(uint2*)(outg2 + (gi*8 + p)*136 + mt*16 + quad*4) = w;
        }
      }
    }
    __syncthreads();
  }

  // ---- C1: ens scores GEMM (M=96 rows (s,p), N=24 (t,h), K=128) ----
  for (int ti = 0; ti < 3; ++ti) {
    int T = wave*3 + ti;
    int mtp = T >> 1, ntp = T & 1;
    f32x4 acc = {0.f,0.f,0.f,0.f};
#pragma unroll
    for (int kt = 0; kt < 4; ++kt) {
      short8 a = *(const short8*)(outg2 + (mtp*16 + l15)*136 + kt*32 + quad*8);
      short8 b = *(const short8*)(qkeB + ((ntp*4 + kt)*64 + lane)*8);
      acc = __builtin_amdgcn_mfma_f32_16x16x32_bf16(a, b, acc, 0, 0, 0);
    }
    int th = ntp*16 + l15;
    if (th < 24) {
      float qb = wsf[QB_ENS + th];
#pragma unroll
      for (int reg = 0; reg < 4; ++reg) {
        int rowE = mtp*16 + quad*4 + reg;
        sce2[((rowE & 7)*24 + th)*16 + (rowE >> 3)] = f2bf((acc[reg] + qb) * 0.125f);
      }
    }
  }
  __syncthreads();

  // ---- C2: softmax over s per (p, t, h) ----
  if (tid < 192) {
    unsigned short* row = sce2 + tid*16;
    float m = -1e30f;
    for (int s = 0; s < 12; ++s) m = fmaxf(m, bf2f(row[s]));
    float ssum = 0.f;
    for (int s = 0; s < 12; ++s) {
      float ev = __expf(bf2f(row[s]) - m);
      ssum += ev;
      row[s] = f2bf(ev);
    }
    float inv = 1.f / ssum;
    for (int s = 0; s < 12; ++s) row[s] = f2bf(bf2f(row[s]) * inv);
  }
  __syncthreads();

  // ---- C3: 4 patches per period: wsum -> batched matvec GEMM -> LN ----
  for (int ph = 0; ph < 2; ++ph) {
    int pbase = ph*4;
    // wsum: XEt4[c = lp*12+t][e' = h*128+e] = sum_s a[p,h,t,s]*outg2[(s,p)][e]
    for (int idx = tid; idx < 1536; idx += 256) {
      int c = idx >> 5, ec = idx & 31;
      int lp = c/12, t = c - (c/12)*12;
      int p = pbase + lp;
      int h = ec >> 4, ecr = ec & 15;
      const unsigned short* arow = sce2 + (p*24 + t*2 + h)*16;
      float a0=0.f,a1=0.f,a2=0.f,a3=0.f,a4=0.f,a5=0.f,a6=0.f,a7=0.f;
      for (int s = 0; s < 12; ++s) {
        float av = bf2f(arow[s]);
        uint4 o = *(const uint4*)(outg2 + (s*8 + p)*136 + ecr*8);
        a0 += av * __uint_as_float(o.x << 16);
        a1 += av * __uint_as_float(o.x & 0xffff0000u);
        a2 += av * __uint_as_float(o.y << 16);
        a3 += av * __uint_as_float(o.y & 0xffff0000u);
        a4 += av * __uint_as_float(o.z << 16);
        a5 += av * __uint_as_float(o.z & 0xffff0000u);
        a6 += av * __uint_as_float(o.w << 16);
        a7 += av * __uint_as_float(o.w & 0xffff0000u);
      }
      uint4 w;
      w.x = (unsigned)f2bf(a0) | ((unsigned)f2bf(a1) << 16);
      w.y = (unsigned)f2bf(a2) | ((unsigned)f2bf(a3) << 16);
      w.z = (unsigned)f2bf(a4) | ((unsigned)f2bf(a5) << 16);
      w.w = (unsigned)f2bf(a6) | ((unsigned)f2bf(a7) << 16);
      *(uint4*)(XEt4 + c*264 + ec*8) = w;
    }
    __syncthreads();

    // batched ens matvec: M=128 r, N=48 (lp,t), K=256
    f32x4 acc[3][2] = {{{0.f,0.f,0.f,0.f},{0.f,0.f,0.f,0.f}},
                       {{0.f,0.f,0.f,0.f},{0.f,0.f,0.f,0.f}},
                       {{0.f,0.f,0.f,0.f},{0.f,0.f,0.f,0.f}}};
#pragma unroll
    for (int kt = 0; kt < 8; ++kt) {
      short8 b0 = *(const short8*)(XEt4 + (0*16 + l15)*264 + kt*32 + quad*8);
      short8 b1 = *(const short8*)(XEt4 + (1*16 + l15)*264 + kt*32 + quad*8);
      short8 b2 = *(const short8*)(XEt4 + (2*16 + l15)*264 + kt*32 + quad*8);
#pragma unroll
      for (int mi = 0; mi < 2; ++mi) {
        int mt = wave*2 + mi;
        short8 a = *(const short8*)(MeB + ((mt*8 + kt)*64 + lane)*8);
        acc[0][mi] = __builtin_amdgcn_mfma_f32_16x16x32_bf16(a, b0, acc[0][mi], 0, 0, 0);
        acc[1][mi] = __builtin_amdgcn_mfma_f32_16x16x32_bf16(a, b1, acc[1][mi], 0, 0, 0);
        acc[2][mi] = __builtin_amdgcn_mfma_f32_16x16x32_bf16(a, b2, acc[2][mi], 0, 0, 0);
      }
    }
    __syncthreads();   // all XEt4 reads done; safe to overwrite with rObuf

    // write rObuf[c][r] = acc + cens (bf16)
#pragma unroll
    for (int nt = 0; nt < 3; ++nt) {
#pragma unroll
      for (int mi = 0; mi < 2; ++mi) {
        int mt = wave*2 + mi;
        int c = nt*16 + l15;
        int rb = mt*16 + quad*4;
        unsigned short t0 = f2bf(acc[nt][mi][0] + wsf[CENS + rb + 0]);
        unsigned short t1 = f2bf(acc[nt][mi][1] + wsf[CENS + rb + 1]);
        unsigned short t2 = f2bf(acc[nt][mi][2] + wsf[CENS + rb + 2]);
        unsigned short t3 = f2bf(acc[nt][mi][3] + wsf[CENS + rb + 3]);
        uint2 w;
        w.x = (unsigned)t0 | ((unsigned)t1 << 16);
        w.y = (unsigned)t2 | ((unsigned)t3 << 16);
        *(uint2*)(rObuf + c*136 + rb) = w;
      }
    }
    __syncthreads();

    // LayerNorm: wave w handles patch pbase+w; no intra-phase barriers
    {
      int lp = wave;
      float s1 = 0.f, s2 = 0.f;
#pragma unroll
      for (int itn = 0; itn < 24; ++itn) {
        int j = lane + itn*64;
        float v = bf2f(rObuf[(lp*12 + (j >> 7))*136 + (j & 127)]);
        s1 += v; s2 += v*v;
      }
#pragma unroll
      for (int off = 32; off > 0; off >>= 1) {
        s1 += __shfl_xor(s1, off);
        s2 += __shfl_xor(s2, off);
      }
      float mean = s1 * (1.f/1536.f);
      float var  = s2 * (1.f/1536.f) - mean*mean;
      float rstd = rsqrtf(var + 1e-5f);
      long nrow = (long)(nbase + pbase + lp) * 1536;
#pragma unroll
      for (int itn = 0; itn < 24; ++itn) {
        int j = lane + itn*64;
        float v = bf2f(rObuf[(lp*12 + (j >> 7))*136 + (j & 127)]);
        out[nrow + j] = (v - mean) * rstd * lgam[j] + lbet[j];
      }
    }
    __syncthreads();
  }
}

// ---------------------------------------------------------------------------
extern "C" void kernel_launch(void* const* d_in, const int* in_sizes, int n_in,
                              void* d_out, int out_size, void* d_ws, size_t ws_size,
                              hipStream_t stream) {
  const float* x   = (const float*)d_in[0];
  const float* cw  = (const float*)d_in[1];
  const float* cb  = (const float*)d_in[2];
  const float* ce  = (const float*)d_in[3];
  const float* cq  = (const float*)d_in[4];
  const float* giw = (const float*)d_in[5];
  const float* gib = (const float*)d_in[6];
  const float* gow = (const float*)d_in[7];
  const float* gob = (const float*)d_in[8];
  const float* eq  = (const float*)d_in[9];
  const float* eiw = (const float*)d_in[10];
  const float* eib = (const float*)d_in[11];
  const float* eow = (const float*)d_in[12];
  const float* eob = (const float*)d_in[13];
  const float* lg  = (const float*)d_in[14];
  const float* lb  = (const float*)d_in[15];

  float* wsf = (float*)d_ws;
  float* cwq = (float*)((char*)d_ws + CWQ_BYTE);
  unsigned short* MgB  = (unsigned short*)((char*)d_ws + MGB_BYTE);
  unsigned short* MeB  = (unsigned short*)((char*)d_ws + MEB_BYTE);
  unsigned short* cw2B = (unsigned short*)((char*)d_ws + CW2B_BYTE);
  unsigned short* qkeB = (unsigned short*)((char*)d_ws + QKEB_BYTE);

  hwe_preA<<<1184, 256, 0, stream>>>(giw, gib, gow, gob, cq, eq, eiw, eib, eow, eob, wsf);
  hwe_pre2<<<48, 128, 0, stream>>>(giw, gib, eiw, eib, wsf);
  hwe_pre3<<<2116, 256, 0, stream>>>(giw, gow, eiw, eow, cw, cb, ce, wsf,
                                     MgB, MeB, cw2B, qkeB, cwq);
  hwe_main<<<1024, 256, 0, stream>>>(x, lg, lb, wsf, cwq,
                                     MgB, MeB, cw2B, qkeB, (float*)d_out);
}

// Round 6
// 274.495 us; speedup vs baseline: 2.7128x; 1.0623x over previous
//
#include <hip/hip_runtime.h>

// ---------------------------------------------------------------------------
// HieraWeatherEmbedding R6: F-fold (group V+out+embed collapsed into one GEMM
// per group) + G-fold (ensemble wsum via MFMA) + register LayerNorm.
// fp32 I/O, bf16 fragments, fp32 accumulate.
// ---------------------------------------------------------------------------

typedef __attribute__((ext_vector_type(8))) short short8;
typedef __attribute__((ext_vector_type(4))) float f32x4;

__constant__ int GOFF[13] = {0,7,14,21,28,35,44,53,62,71,80,97,103};
__constant__ int K5A[12]  = {35,35,35,35,35,45,45,45,45,45,85,30};
__constant__ int SLOTS3[12] = {3,3,3,3,3,3,3,3,3,3,6,2};
__constant__ int FOFFA[12] = {0,3,6,9,12,15,18,21,24,27,30,36};   // slot offsets (total 38)
__constant__ int EOFF0[7] = {0,560,1120,1680,2240,2800,3520};
__constant__ int EOFF1[7] = {0,720,1440,2160,2880,4240,4720};
__constant__ int GSLOT[103] = {
  3,8,13,18,23,28,33,
  4,9,14,19,24,29,34,
  2,7,12,17,22,27,32,
  1,6,11,16,21,26,31,
  0,5,10,15,20,25,30,
  3,8,13,18,23,28,33,38,43,
  4,9,14,19,24,29,34,39,44,
  2,7,12,17,22,27,32,37,42,
  1,6,11,16,21,26,31,36,41,
  0,5,10,15,20,25,30,35,40,
  45,46,47,48,49,50,51,52,53,54,55,56,57,58,59,60,61,
  62,63,64,65,66,67};
__constant__ int GIDX[103] = {
  0,0,0,0,0,0,0, 1,1,1,1,1,1,1, 2,2,2,2,2,2,2, 3,3,3,3,3,3,3, 4,4,4,4,4,4,4,
  5,5,5,5,5,5,5,5,5, 6,6,6,6,6,6,6,6,6, 7,7,7,7,7,7,7,7,7, 8,8,8,8,8,8,8,8,8,
  9,9,9,9,9,9,9,9,9,
  10,10,10,10,10,10,10,10,10,10,10,10,10,10,10,10,10,
  11,11,11,11,11,11};

// fp32 workspace region (float offsets)
#define QK_GRP 0        // [12][2][128]
#define QK_ENS 3072     // [24][128]
#define QB_GRP 6144     // [12][2]
#define QB_ENS 6176     // [24]
#define CGRP   6208     // [12][128]
#define CENS   7744     // [128]
#define QF_GRP 7872     // [12][128]
#define QF_ENS 9408     // [12][128]  (ends 9536 floats)
// byte offsets
#define CWQ_BYTE   43776    // float [103][2][8]
#define MPL_BYTE   50432    // float [12][128][256]   (1572864 B)
#define MEB_BYTE   1623296  // ushort [8mt][8kt][64][8] (65536 B)
#define QKEB_BYTE  1688832  // ushort [2nt][4kt][64][8] (8192 B)
#define FWS_BYTE   1697024  // ushort 304 frags * 512  (311296 B)

__device__ __forceinline__ float bf2f(unsigned short s) {
  return __uint_as_float(((unsigned)s) << 16);
}
__device__ __forceinline__ unsigned short f2bf(float f) {
  unsigned u = __float_as_uint(f);
  u += 0x7fffu + ((u >> 16) & 1u);
  return (unsigned short)(u >> 16);
}

// ---------------------------------------------------------------------------
// preA: q_full + folded bias vectors (wave per output, lanes over K) + F-zero
// ---------------------------------------------------------------------------
__global__ void hwe_preA(const float* __restrict__ giw, const float* __restrict__ gib,
                         const float* __restrict__ gow, const float* __restrict__ gob,
                         const float* __restrict__ cq,  const float* __restrict__ eq,
                         const float* __restrict__ eiw, const float* __restrict__ eib,
                         const float* __restrict__ eow, const float* __restrict__ eob,
                         float* __restrict__ wsf, unsigned short* __restrict__ Fws) {
  if (blockIdx.x >= 1184) {   // zero F table: 311296 B = 19456 uint4
    int idx = (blockIdx.x - 1184)*256 + threadIdx.x;
    if (idx < 19456) ((uint4*)Fws)[idx] = (uint4){0,0,0,0};
    return;
  }
  int id = blockIdx.x*4 + (threadIdx.x >> 6);
  int lane = threadIdx.x & 63;
  float acc, bias;
  int dst;
  if (id < 1536) {                       // QF_GRP
    int i = id >> 7, d = id & 127;
    const float* wrow = giw + i*49152 + d*128;
    const float* qv = cq + i*128;
    acc = wrow[lane]*qv[lane] + wrow[lane+64]*qv[lane+64];
    bias = gib[i*384 + d];
    dst = QF_GRP + id;
  } else if (id < 3072) {                // CGRP
    int r = id - 1536; int i = r >> 7, d = r & 127;
    const float* wrow = gow + i*16384 + d*128;
    const float* bv = gib + i*384 + 256;
    acc = wrow[lane]*bv[lane] + wrow[lane+64]*bv[lane+64];
    bias = gob[i*128 + d];
    dst = CGRP + r;
  } else if (id < 4608) {                // QF_ENS
    int r = id - 3072; int t = r >> 7, d = r & 127;
    const float* wrow = eiw + d*128;
    const float* qv = eq + t*128;
    acc = wrow[lane]*qv[lane] + wrow[lane+64]*qv[lane+64];
    bias = eib[d];
    dst = QF_ENS + r;
  } else {                               // CENS
    int d = id - 4608;
    const float* wrow = eow + d*128;
    const float* bv = eib + 256;
    acc = wrow[lane]*bv[lane] + wrow[lane+64]*bv[lane+64];
    bias = eob[d];
    dst = CENS + d;
  }
#pragma unroll
  for (int off = 32; off > 0; off >>= 1) acc += __shfl_down(acc, off);
  if (lane == 0) wsf[dst] = acc + bias;
}

// ---------------------------------------------------------------------------
// pre2: qk = Wk^T q per head, qb = q.bk
// ---------------------------------------------------------------------------
__global__ void hwe_pre2(const float* __restrict__ giw, const float* __restrict__ gib,
                         const float* __restrict__ eiw, const float* __restrict__ eib,
                         float* __restrict__ wsf) {
  int blk = blockIdx.x, e = threadIdx.x;
  if (blk < 24) {
    int i = blk >> 1, h = blk & 1;
    float a0=0.f,a1=0.f,a2=0.f,a3=0.f;
    for (int dp = 0; dp < 64; dp += 4) {
      a0 += wsf[QF_GRP + i*128 + h*64 + dp+0] * giw[i*49152 + (128 + h*64 + dp+0)*128 + e];
      a1 += wsf[QF_GRP + i*128 + h*64 + dp+1] * giw[i*49152 + (128 + h*64 + dp+1)*128 + e];
      a2 += wsf[QF_GRP + i*128 + h*64 + dp+2] * giw[i*49152 + (128 + h*64 + dp+2)*128 + e];
      a3 += wsf[QF_GRP + i*128 + h*64 + dp+3] * giw[i*49152 + (128 + h*64 + dp+3)*128 + e];
    }
    wsf[QK_GRP + (i*2 + h)*128 + e] = (a0+a1)+(a2+a3);
    if (e == 0) {
      float ab = 0.f;
      for (int dp = 0; dp < 64; ++dp)
        ab += wsf[QF_GRP + i*128 + h*64 + dp] * gib[i*384 + 128 + h*64 + dp];
      wsf[QB_GRP + i*2 + h] = ab;
    }
  } else {
    int tb = blk - 24, t = tb >> 1, h = tb & 1;
    float a0=0.f,a1=0.f,a2=0.f,a3=0.f;
    for (int dp = 0; dp < 64; dp += 4) {
      a0 += wsf[QF_ENS + t*128 + h*64 + dp+0] * eiw[(128 + h*64 + dp+0)*128 + e];
      a1 += wsf[QF_ENS + t*128 + h*64 + dp+1] * eiw[(128 + h*64 + dp+1)*128 + e];
      a2 += wsf[QF_ENS + t*128 + h*64 + dp+2] * eiw[(128 + h*64 + dp+2)*128 + e];
      a3 += wsf[QF_ENS + t*128 + h*64 + dp+3] * eiw[(128 + h*64 + dp+3)*128 + e];
    }
    wsf[QK_ENS + (t*2 + h)*128 + e] = (a0+a1)+(a2+a3);
    if (e == 0) {
      float ab = 0.f;
      for (int dp = 0; dp < 64; ++dp)
        ab += wsf[QF_ENS + t*128 + h*64 + dp] * eib[128 + h*64 + dp];
      wsf[QB_ENS + t*2 + h] = ab;
    }
  }
}

// ---------------------------------------------------------------------------
// pre3: Mplain (fp32, coalesced), MeB (A-frag), qkeB (B-frag), cwq
// ---------------------------------------------------------------------------
__global__ void hwe_pre3(const float* __restrict__ giw, const float* __restrict__ gow,
                         const float* __restrict__ eiw, const float* __restrict__ eow,
                         const float* __restrict__ cw,  const float* __restrict__ cb,
                         const float* __restrict__ ce,  const float* __restrict__ wsf,
                         float* __restrict__ Mplain, unsigned short* __restrict__ MeB,
                         unsigned short* __restrict__ qkeB, float* __restrict__ cwq) {
  int blk = blockIdx.x, tid = threadIdx.x;
  if (blk < 1536) {                 // Mplain[gi][r][ep] = sum_hd Wout[r][h64+hd]*Wv[h64+hd][e]
    int gi = blk >> 7, r = blk & 127;
    int ep = tid;                   // ep = h*128 + e
    int h = ep >> 7, e = ep & 127;
    const float* wo = gow + gi*16384 + r*128 + h*64;
    const float* wv = giw + gi*49152 + (256 + h*64)*128 + e;
    float a0=0.f,a1=0.f,a2=0.f,a3=0.f;
    for (int hd = 0; hd < 64; hd += 4) {
      a0 += wo[hd+0] * wv[(hd+0)*128];
      a1 += wo[hd+1] * wv[(hd+1)*128];
      a2 += wo[hd+2] * wv[(hd+2)*128];
      a3 += wo[hd+3] * wv[(hd+3)*128];
    }
    Mplain[(gi*128 + r)*256 + ep] = (a0+a1)+(a2+a3);
  } else if (blk < 1664) {          // MeB A-frag swizzle
    int f2 = (blk - 1536)*256 + tid;
    int r = f2 >> 8, ep = f2 & 255;
    int h = ep >> 7, e = ep & 127;
    const float* wo = eow + r*128 + h*64;
    const float* wv = eiw + (256 + h*64)*128 + e;
    float a0=0.f,a1=0.f,a2=0.f,a3=0.f;
    for (int hd = 0; hd < 64; hd += 4) {
      a0 += wo[hd+0] * wv[(hd+0)*128];
      a1 += wo[hd+1] * wv[(hd+1)*128];
      a2 += wo[hd+2] * wv[(hd+2)*128];
      a3 += wo[hd+3] * wv[(hd+3)*128];
    }
    float acc = (a0+a1)+(a2+a3);
    int mt = r >> 4, lr = r & 15, kt = ep >> 5, q = (ep >> 3) & 3, j = ep & 7;
    MeB[((mt*8 + kt)*64 + (q*16 + lr))*8 + j] = f2bf(acc);
  } else if (blk < 1680) {          // qkeB B-frag
    int f4 = (blk - 1664)*256 + tid;   // [0,4096)
    int lane = (f4 >> 3) & 63, j = f4 & 7;
    int th = ((f4 >> 11) & 1)*16 + (lane & 15);
    int kt = (f4 >> 9) & 3;
    float val = (th < 24) ? wsf[QK_ENS + th*128 + kt*32 + (lane >> 4)*8 + j] : 0.f;
    qkeB[f4] = f2bf(val);
  } else {                          // cwq: wave per (gg,h)
    int wid = (blk - 1680)*4 + (tid >> 6);
    int lane = tid & 63;
    if (wid < 206) {
      int gg = wid >> 1, h = wid & 1;
      int gi = GIDX[gg];
      int s = GSLOT[gg];
      int v = (s < 45) ? s : s + 20;
      const float* qk = wsf + QK_GRP + (gi*2 + h)*128;
      float q0 = qk[lane], q1 = qk[lane + 64];
      float a[5];
#pragma unroll
      for (int pp = 0; pp < 4; ++pp)
        a[pp] = cw[(v*4 + pp)*128 + lane]*q0 + cw[(v*4 + pp)*128 + lane + 64]*q1;
      a[4] = (cb[v*128 + lane] + ce[v*128 + lane])*q0 +
             (cb[v*128 + lane + 64] + ce[v*128 + lane + 64])*q1;
#pragma unroll
      for (int off = 32; off > 0; off >>= 1)
#pragma unroll
        for (int kk = 0; kk < 5; ++kk) a[kk] += __shfl_down(a[kk], off);
      if (lane == 0) {
        float* o = cwq + (gg*2 + h)*8;
        o[0] = a[0]*0.125f; o[1] = a[1]*0.125f; o[2] = a[2]*0.125f; o[3] = a[3]*0.125f;
        o[4] = (a[4] + wsf[QB_GRP + gi*2 + h]) * 0.125f;
      }
    }
  }
}

// ---------------------------------------------------------------------------
// pre4: F_h[r][k] = sum_e M_h[r][e]*cw2[k][e], written as A-frags.
// 192 blocks = (gi, h, mt of 16 r). LDS-staged, conflict-padded stride 65 uint.
// ---------------------------------------------------------------------------
__global__ void hwe_pre4(const float* __restrict__ cw, const float* __restrict__ cb,
                         const float* __restrict__ ce, const float* __restrict__ Mplain,
                         unsigned short* __restrict__ Fws) {
  __shared__ __align__(16) unsigned short M16[16*130];    // [rr][e], uint stride 65
  __shared__ __align__(16) unsigned short cwl[85*130];    // [k][e],  uint stride 65
  int bi = blockIdx.x, tid = threadIdx.x;
  int gi = bi >> 4, h = (bi >> 3) & 1, mt = bi & 7;
  int go = GOFF[gi], K5 = K5A[gi], S = SLOTS3[gi];
  int r0 = mt*16;
  // stage M tile (16 r x 128 e)
  for (int idx = tid; idx < 2048; idx += 256) {
    int rr = idx >> 7, e = idx & 127;
    M16[rr*130 + e] = f2bf(Mplain[(gi*128 + r0 + rr)*256 + h*128 + e]);
  }
  // stage cw2 rows (K5 x 128)
  for (int idx = tid; idx < K5*128; idx += 256) {
    int k = idx >> 7, e = idx & 127;
    int q = (k*205) >> 10;
    int pp = k - q*5;
    int s = GSLOT[go + q];
    int v = (s < 45) ? s : s + 20;
    float val = (pp < 4) ? cw[(v*4 + pp)*128 + e] : (cb[v*128 + e] + ce[v*128 + e]);
    cwl[k*130 + e] = f2bf(val);
  }
  __syncthreads();
  const unsigned* M32 = (const unsigned*)M16;
  const unsigned* C32 = (const unsigned*)cwl;
  for (int o = tid; o < 16*K5; o += 256) {
    int k = o >> 4, rr = o & 15;
    float acc = 0.f;
#pragma unroll 8
    for (int e2 = 0; e2 < 64; ++e2) {
      unsigned m = M32[rr*65 + e2];
      unsigned c = C32[k*65 + e2];
      acc += __uint_as_float(m << 16) * __uint_as_float(c << 16);
      acc += __uint_as_float(m & 0xffff0000u) * __uint_as_float(c & 0xffff0000u);
    }
    int kpp = h*K5 + k;            // k'' in [0, 2*K5)
    int ktl = kpp >> 5;
    int addr = (FOFFA[gi]*8 + mt*S + ktl)*512 + ((kpp >> 3) & 3)*128 + rr*8 + (kpp & 7);
    Fws[addr] = f2bf(acc);
  }
}

// ---------------------------------------------------------------------------
// Main kernel. grid 1024, block 256 (4 waves). 8 patches per block.
// LDS (bytes), total 62656:
//   region0 [0,28160):
//     A/B: xpB@0 [8p][68][4]us 4352; scb@4352 [8p][2h][104]us 3328;
//          wpAll@7680 [20slot][64][8]us 20480
//     C:   G@0 [2lp][128r][32k'']us 16384; apB@16384 [8p][64][8]us 8192
//   outg2@28160 [104][136]us 28288   (rows 96..103 zeroed = s-phantom)
//   sce2@56448 [192][16]us 6144
//   stats@62592 float[16]
// ---------------------------------------------------------------------------
__global__ __launch_bounds__(256, 2) void hwe_main(
    const float* __restrict__ x,
    const float* __restrict__ lgam, const float* __restrict__ lbet,
    const float* __restrict__ wsf,  const float* __restrict__ cwq,
    const unsigned short* __restrict__ Fws, const unsigned short* __restrict__ MeB,
    const unsigned short* __restrict__ qkeB,
    float* __restrict__ out) {
  __shared__ __align__(16) unsigned char smem[62656];
  unsigned short* xpB   = (unsigned short*)(smem);
  unsigned short* scb   = (unsigned short*)(smem + 4352);
  unsigned short* wpAll = (unsigned short*)(smem + 7680);
  unsigned short* Gl    = (unsigned short*)(smem);          // C overlay
  unsigned short* apB   = (unsigned short*)(smem + 16384);  // C overlay
  unsigned short* outg2 = (unsigned short*)(smem + 28160);
  unsigned short* sce2  = (unsigned short*)(smem + 56448);
  float*          stats = (float*)(smem + 62592);

  const int tid  = threadIdx.x;
  const int wave = tid >> 6;
  const int lane = tid & 63;
  const int quad = lane >> 4;
  const int l15  = lane & 15;

  const int hi   = blockIdx.x >> 4;
  const int wib  = (blockIdx.x & 15) << 3;
  const int nbase = hi*128 + wib;

  // ---- A1: pixels + zero phantom outg2 rows 96..103 ----
  for (int idx = tid; idx < 2176; idx += 256) {
    int c = idx & 15, r = (idx >> 4) & 1, s = idx >> 5;
    int v = (s < 45) ? s : s + 20;
    float val = x[(v*128 + 2*hi + r)*256 + 2*wib + c];
    int p = c >> 1, pp = r*2 + (c & 1);
    xpB[(p*68 + s)*4 + pp] = f2bf(val);
  }
  for (int idx = tid; idx < 544; idx += 256)
    ((unsigned*)outg2)[96*68 + idx] = 0;
  __syncthreads();

  // ---- A2: group scores via cwq fold ----
  for (int idx = tid; idx < 1648; idx += 256) {
    int h = idx & 1, p = (idx >> 1) & 7, gg = idx >> 4;
    int s = GSLOT[gg];
    const float* c = cwq + (gg*2 + h)*8;
    const unsigned short* xr = xpB + (p*68 + s)*4;
    float acc = c[4] + bf2f(xr[0])*c[0] + bf2f(xr[1])*c[1]
                     + bf2f(xr[2])*c[2] + bf2f(xr[3])*c[3];
    scb[(p*2 + h)*104 + gg] = f2bf(acc);
  }
  __syncthreads();

  // ---- A3: softmax per (p,h,group) ----
  if (tid < 192) {
    int gi = tid % 12, h = (tid / 12) & 1, p = tid / 24;
    int go = GOFF[gi], G = GOFF[gi+1] - go;
    unsigned short* row = scb + (p*2 + h)*104 + go;
    float m = -1e30f;
    for (int g = 0; g < G; ++g) m = fmaxf(m, bf2f(row[g]));
    float ssum = 0.f;
    for (int g = 0; g < G; ++g) {
      float ev = __expf(bf2f(row[g]) - m);
      ssum += ev;
      row[g] = f2bf(ev);
    }
    float inv = 1.f / ssum;
    for (int g = 0; g < G; ++g) row[g] = f2bf(bf2f(row[g]) * inv);
  }
  __syncthreads();

  // ---- Phase B: two halves of 6 groups; F-folded single GEMM per group ----
  for (int hb = 0; hb < 2; ++hb) {
    const int nsl = hb ? 20 : 18;
    const int sbase = hb ? 18 : 0;
    // zero wp slots
    for (int i = tid; i < nsl*64; i += 256)
      *(uint4*)(wpAll + i*8) = (uint4){0,0,0,0};
    __syncthreads();
    // sparse fill of valid entries
    {
      const int total = hb ? 4720 : 3520;
      for (int idx = tid; idx < total; idx += 256) {
        int gil = 0;
#pragma unroll
        for (int t6 = 1; t6 < 6; ++t6) {
          int eo = hb ? EOFF1[t6] : EOFF0[t6];
          if (idx >= eo) gil = t6;
        }
        int gi = hb*6 + gil;
        int local = idx - (hb ? EOFF1[gil] : EOFF0[gil]);
        int kpp = local >> 3, p = local & 7;
        int K5 = K5A[gi];
        int h = (kpp >= K5) ? 1 : 0;
        int k = kpp - (h ? K5 : 0);
        int q = (k*205) >> 10;
        int pp = k - q*5;
        int gg = GOFF[gi] + q;
        float a = bf2f(scb[(p*2 + h)*104 + gg]);
        float val = (pp < 4) ? a * bf2f(xpB[(p*68 + GSLOT[gg])*4 + pp]) : a;
        int ls = (FOFFA[gi] - sbase) + (kpp >> 5);
        wpAll[ls*512 + ((kpp >> 3) & 3)*128 + p*8 + (kpp & 7)] = f2bf(val);
      }
    }
    __syncthreads();
    // GEMM: 48 (group,mt) pairs over 4 waves
    for (int i = 0; i < 12; ++i) {
      int pi = i*4 + wave;
      int gil = pi >> 3, mt = pi & 7;
      int gi = hb*6 + gil;
      int S = SLOTS3[gi];
      int lbase = FOFFA[gi] - sbase;
      f32x4 acc = {0.f,0.f,0.f,0.f};
      for (int kt = 0; kt < S; ++kt) {
        short8 a = *(const short8*)(Fws + (FOFFA[gi]*8 + mt*S + kt)*512 + lane*8);
        short8 b = *(const short8*)(wpAll + (lbase + kt)*512 + lane*8);
        acc = __builtin_amdgcn_mfma_f32_16x16x32_bf16(a, b, acc, 0, 0, 0);
      }
      if (l15 < 8) {
        int p = l15;
        int rb = mt*16 + quad*4;
        unsigned short t0 = f2bf(acc[0] + wsf[CGRP + gi*128 + rb + 0]);
        unsigned short t1 = f2bf(acc[1] + wsf[CGRP + gi*128 + rb + 1]);
        unsigned short t2 = f2bf(acc[2] + wsf[CGRP + gi*128 + rb + 2]);
        unsigned short t3 = f2bf(acc[3] + wsf[CGRP + gi*128 + rb + 3]);
        uint2 w;
        w.x = (unsigned)t0 | ((unsigned)t1 << 16);
        w.y = (unsigned)t2 | ((unsigned)t3 << 16);
        *(uint2*)(outg2 + (gi*8 + p)*136 + rb) = w;
      }
    }
    __syncthreads();
  }

  // ---- C1: ens scores GEMM (M=96 rows (s,p), N=24 (t,h), K=128) ----
  for (int ti = 0; ti < 3; ++ti) {
    int T = wave*3 + ti;
    int mtp = T >> 1, ntp = T & 1;
    f32x4 acc = {0.f,0.f,0.f,0.f};
#pragma unroll
    for (int kt = 0; kt < 4; ++kt) {
      short8 a = *(const short8*)(outg2 + (mtp*16 + l15)*136 + kt*32 + quad*8);
      short8 b = *(const short8*)(qkeB + ((ntp*4 + kt)*64 + lane)*8);
      acc = __builtin_amdgcn_mfma_f32_16x16x32_bf16(a, b, acc, 0, 0, 0);
    }
    int th = ntp*16 + l15;
    if (th < 24) {
      float qb = wsf[QB_ENS + th];
#pragma unroll
      for (int reg = 0; reg < 4; ++reg) {
        int rowE = mtp*16 + quad*4 + reg;
        sce2[((rowE & 7)*24 + th)*16 + (rowE >> 3)] = f2bf((acc[reg] + qb) * 0.125f);
      }
    }
  }
  __syncthreads();

  // ---- C2: softmax over s per (p, t, h) ----
  if (tid < 192) {
    unsigned short* row = sce2 + tid*16;
    float m = -1e30f;
    for (int s = 0; s < 12; ++s) m = fmaxf(m, bf2f(row[s]));
    float ssum = 0.f;
    for (int s = 0; s < 12; ++s) {
      float ev = __expf(bf2f(row[s]) - m);
      ssum += ev;
      row[s] = f2bf(ev);
    }
    float inv = 1.f / ssum;
    for (int s = 0; s < 12; ++s) row[s] = f2bf(bf2f(row[s]) * inv);
  }
  __syncthreads();

  // ---- apB: attn weights as B-frags  B[k''=(h*16+s)][n=t] per p ----
  for (int idx = tid; idx < 4096; idx += 256) {
    int p = idx >> 9, r9 = idx & 511;
    int ln = r9 >> 3, j = r9 & 7;
    int t = ln & 15, qd = ln >> 4;
    int kpp = qd*8 + j;
    int h = kpp >> 4, s = kpp & 15;
    unsigned short v = 0;
    if (s < 12 && t < 12) v = sce2[(p*24 + t*2 + h)*16 + s];
    apB[p*512 + ln*8 + j] = v;
  }
  // preload cens for this thread's (r) positions
  float cens0[4], cens1[4];
#pragma unroll
  for (int reg = 0; reg < 4; ++reg) {
    cens0[reg] = wsf[CENS + (wave*2 + 0)*16 + quad*4 + reg];
    cens1[reg] = wsf[CENS + (wave*2 + 1)*16 + quad*4 + reg];
  }
  __syncthreads();

  // ---- C3: 2 patches per period: G-GEMM -> R-GEMM -> register LayerNorm ----
  for (int pp2 = 0; pp2 < 4; ++pp2) {
    // G_h[r][s] = M_h @ O_p^T ; per wave mt = wave*2+{0,1}
    f32x4 g[2][2][2];  // [lp][mi][h]
#pragma unroll
    for (int lp = 0; lp < 2; ++lp)
#pragma unroll
      for (int mi = 0; mi < 2; ++mi)
#pragma unroll
        for (int h = 0; h < 2; ++h) g[lp][mi][h] = (f32x4){0.f,0.f,0.f,0.f};
#pragma unroll
    for (int lp = 0; lp < 2; ++lp) {
      int p = pp2*2 + lp;
      int brow = (l15 < 12 ? l15 : 12)*8 + p;   // phantom s -> zero row 96+p
#pragma unroll
      for (int h = 0; h < 2; ++h) {
#pragma unroll
        for (int kt = 0; kt < 4; ++kt) {
          short8 b = *(const short8*)(outg2 + brow*136 + kt*32 + quad*8);
          short8 a0 = *(const short8*)(MeB + (((wave*2 + 0)*8 + h*4 + kt)*64 + lane)*8);
          short8 a1 = *(const short8*)(MeB + (((wave*2 + 1)*8 + h*4 + kt)*64 + lane)*8);
          g[lp][0][h] = __builtin_amdgcn_mfma_f32_16x16x32_bf16(a0, b, g[lp][0][h], 0, 0, 0);
          g[lp][1][h] = __builtin_amdgcn_mfma_f32_16x16x32_bf16(a1, b, g[lp][1][h], 0, 0, 0);
        }
      }
    }
    // write G to LDS: Gl[lp][r][h*16 + s]
#pragma unroll
    for (int lp = 0; lp < 2; ++lp)
#pragma unroll
      for (int mi = 0; mi < 2; ++mi)
#pragma unroll
        for (int h = 0; h < 2; ++h)
#pragma unroll
          for (int reg = 0; reg < 4; ++reg) {
            int r = (wave*2 + mi)*16 + quad*4 + reg;
            Gl[lp*4096 + r*32 + h*16 + l15] = f2bf(g[lp][mi][h][reg]);
          }
    __syncthreads();

    // R-GEMM: R[r][t] = G @ a'  (K=32), then stats from registers
    f32x4 rr[2][2];   // [lp][mi]
    float s1[2] = {0.f, 0.f}, s2[2] = {0.f, 0.f};
#pragma unroll
    for (int lp = 0; lp < 2; ++lp) {
      int p = pp2*2 + lp;
      short8 bfrag = *(const short8*)(apB + p*512 + lane*8);
#pragma unroll
      for (int mi = 0; mi < 2; ++mi) {
        int mt2 = wave*2 + mi;
        short8 afrag = *(const short8*)(Gl + lp*4096 + (mt2*16 + l15)*32 + quad*8);
        f32x4 acc = {0.f,0.f,0.f,0.f};
        acc = __builtin_amdgcn_mfma_f32_16x16x32_bf16(afrag, bfrag, acc, 0, 0, 0);
#pragma unroll
        for (int reg = 0; reg < 4; ++reg)
          acc[reg] += (mi ? cens1[reg] : cens0[reg]);
        rr[lp][mi] = acc;
        if (l15 < 12) {
#pragma unroll
          for (int reg = 0; reg < 4; ++reg) {
            float v = acc[reg];
            s1[lp] += v; s2[lp] += v*v;
          }
        }
      }
    }
#pragma unroll
    for (int off = 32; off > 0; off >>= 1) {
#pragma unroll
      for (int lp = 0; lp < 2; ++lp) {
        s1[lp] += __shfl_xor(s1[lp], off);
        s2[lp] += __shfl_xor(s2[lp], off);
      }
    }
    if (lane == 0) {
#pragma unroll
      for (int lp = 0; lp < 2; ++lp) {
        stats[lp*4 + wave] = s1[lp];
        stats[8 + lp*4 + wave] = s2[lp];
      }
    }
    __syncthreads();
    // normalize + store (C row = (r, t): out j = t*128 + r)
#pragma unroll
    for (int lp = 0; lp < 2; ++lp) {
      float t1 = stats[lp*4+0] + stats[lp*4+1] + stats[lp*4+2] + stats[lp*4+3];
      float t2 = stats[8+lp*4+0] + stats[8+lp*4+1] + stats[8+lp*4+2] + stats[8+lp*4+3];
      float mean = t1 * (1.f/1536.f);
      float var  = t2 * (1.f/1536.f) - mean*mean;
      float rstd = rsqrtf(var + 1e-5f);
      if (l15 < 12) {
        long nrow = (long)(nbase + pp2*2 + lp) * 1536;
#pragma unroll
        for (int mi = 0; mi < 2; ++mi) {
          int rb = (wave*2 + mi)*16 + quad*4;
          int j = l15*128 + rb;
          float4 gm = *(const float4*)(lgam + j);
          float4 bt = *(const float4*)(lbet + j);
          float4 o;
          o.x = (rr[lp][mi][0] - mean)*rstd*gm.x + bt.x;
          o.y = (rr[lp][mi][1] - mean)*rstd*gm.y + bt.y;
          o.z = (rr[lp][mi][2] - mean)*rstd*gm.z + bt.z;
          o.w = (rr[lp][mi][3] - mean)*rstd*gm.w + bt.w;
          *(float4*)(out + nrow + j) = o;
        }
      }
    }
    __syncthreads();
  }
}

// ---------------------------------------------------------------------------
extern "C" void kernel_launch(void* const* d_in, const int* in_sizes, int n_in,
                              void* d_out, int out_size, void* d_ws, size_t ws_size,
                              hipStream_t stream) {
  const float* x   = (const float*)d_in[0];
  const float* cw  = (const float*)d_in[1];
  const float* cb  = (const float*)d_in[2];
  const float* ce  = (const float*)d_in[3];
  const float* cq  = (const float*)d_in[4];
  const float* giw = (const float*)d_in[5];
  const float* gib = (const float*)d_in[6];
  const float* gow = (const float*)d_in[7];
  const float* gob = (const float*)d_in[8];
  const float* eq  = (const float*)d_in[9];
  const float* eiw = (const float*)d_in[10];
  const float* eib = (const float*)d_in[11];
  const float* eow = (const float*)d_in[12];
  const float* eob = (const float*)d_in[13];
  const float* lg  = (const float*)d_in[14];
  const float* lb  = (const float*)d_in[15];

  float* wsf = (float*)d_ws;
  float* cwq = (float*)((char*)d_ws + CWQ_BYTE);
  float* Mplain = (float*)((char*)d_ws + MPL_BYTE);
  unsigned short* MeB  = (unsigned short*)((char*)d_ws + MEB_BYTE);
  unsigned short* qkeB = (unsigned short*)((char*)d_ws + QKEB_BYTE);
  unsigned short* Fws  = (unsigned short*)((char*)d_ws + FWS_BYTE);

  hwe_preA<<<1260, 256, 0, stream>>>(giw, gib, gow, gob, cq, eq, eiw, eib, eow, eob,
                                     wsf, Fws);
  hwe_pre2<<<48, 128, 0, stream>>>(giw, gib, eiw, eib, wsf);
  hwe_pre3<<<1732, 256, 0, stream>>>(giw, gow, eiw, eow, cw, cb, ce, wsf,
                                     Mplain, MeB, qkeB, cwq);
  hwe_pre4<<<192, 256, 0, stream>>>(cw, cb, ce, Mplain, Fws);
  hwe_main<<<1024, 256, 0, stream>>>(x, lg, lb, wsf, cwq, Fws, MeB, qkeB,
                                     (float*)d_out);
}

// Round 7
// 273.373 us; speedup vs baseline: 2.7239x; 1.0041x over previous
//
#include <hip/hip_runtime.h>

// ---------------------------------------------------------------------------
// HieraWeatherEmbedding R7: 3-launch pipeline (P1: QK direct + M tables;
// P2: F-build + qkeB + cwq; main). Gl conflict fix (stride 40), MeB register
// preload. fp32 I/O, bf16 fragments, fp32 accumulate.
// ---------------------------------------------------------------------------

typedef __attribute__((ext_vector_type(8))) short short8;
typedef __attribute__((ext_vector_type(4))) float f32x4;

__constant__ int GOFF[13] = {0,7,14,21,28,35,44,53,62,71,80,97,103};
__constant__ int K5A[12]  = {35,35,35,35,35,45,45,45,45,45,85,30};
__constant__ int SLOTS3[12] = {3,3,3,3,3,3,3,3,3,3,6,2};
__constant__ int FOFFA[12] = {0,3,6,9,12,15,18,21,24,27,30,36};   // slot offsets (total 38)
__constant__ int EOFF0[7] = {0,560,1120,1680,2240,2800,3520};
__constant__ int EOFF1[7] = {0,720,1440,2160,2880,4240,4720};
__constant__ int GSLOT[103] = {
  3,8,13,18,23,28,33,
  4,9,14,19,24,29,34,
  2,7,12,17,22,27,32,
  1,6,11,16,21,26,31,
  0,5,10,15,20,25,30,
  3,8,13,18,23,28,33,38,43,
  4,9,14,19,24,29,34,39,44,
  2,7,12,17,22,27,32,37,42,
  1,6,11,16,21,26,31,36,41,
  0,5,10,15,20,25,30,35,40,
  45,46,47,48,49,50,51,52,53,54,55,56,57,58,59,60,61,
  62,63,64,65,66,67};
__constant__ int GIDX[103] = {
  0,0,0,0,0,0,0, 1,1,1,1,1,1,1, 2,2,2,2,2,2,2, 3,3,3,3,3,3,3, 4,4,4,4,4,4,4,
  5,5,5,5,5,5,5,5,5, 6,6,6,6,6,6,6,6,6, 7,7,7,7,7,7,7,7,7, 8,8,8,8,8,8,8,8,8,
  9,9,9,9,9,9,9,9,9,
  10,10,10,10,10,10,10,10,10,10,10,10,10,10,10,10,10,
  11,11,11,11,11,11};

// fp32 workspace region (float offsets)
#define QK_GRP 0        // [12][2][128]
#define QK_ENS 3072     // [24][128]
#define QB_GRP 6144     // [12][2]
#define QB_ENS 6176     // [24]
#define CGRP   6208     // [12][128]
#define CENS   7744     // [128]
// byte offsets
#define CWQ_BYTE   43776    // float [103][2][8]
#define MPL_BYTE   50432    // float [12][128][256]   (1572864 B)
#define MEB_BYTE   1623296  // ushort [8mt][8kt][64][8] (65536 B)
#define QKEB_BYTE  1688832  // ushort [2nt][4kt][64][8] (8192 B)
#define FWS_BYTE   1697024  // ushort 304 frags * 512  (311296 B)

__device__ __forceinline__ float bf2f(unsigned short s) {
  return __uint_as_float(((unsigned)s) << 16);
}
__device__ __forceinline__ unsigned short f2bf(float f) {
  unsigned u = __float_as_uint(f);
  u += 0x7fffu + ((u >> 16) & 1u);
  return (unsigned short)(u >> 16);
}

// ---------------------------------------------------------------------------
// P1: QK/QB direct (two-phase in-block), CGRP, CENS, Mplain, MeB, F-zero.
// Grid 2204 x 256.
// ---------------------------------------------------------------------------
__global__ void hwe_p1(const float* __restrict__ giw, const float* __restrict__ gib,
                       const float* __restrict__ gow, const float* __restrict__ gob,
                       const float* __restrict__ cq,  const float* __restrict__ eq,
                       const float* __restrict__ eiw, const float* __restrict__ eib,
                       const float* __restrict__ eow, const float* __restrict__ eob,
                       float* __restrict__ wsf, float* __restrict__ Mplain,
                       unsigned short* __restrict__ MeB, unsigned short* __restrict__ Fws) {
  int blk = blockIdx.x, tid = threadIdx.x;
  int wave = tid >> 6, lane = tid & 63;
  if (blk < 48) {                        // QK + QB for (i,h) grp / (t,h) ens
    __shared__ float qf[64];
    bool ens = blk >= 24;
    int bi = ens ? blk - 24 : blk;
    int i = bi >> 1, h = bi & 1;
    const float* W  = ens ? eiw : giw + i*49152;   // [384][128]
    const float* bv = ens ? eib : gib + i*384;     // [384]
    const float* qv = ens ? eq + i*128 : cq + i*128;
    // phase 1: qf[dp] = bv[h*64+dp] + W[h*64+dp][:].qv
    for (int it = 0; it < 16; ++it) {
      int dp = it*4 + wave;
      const float* wrow = W + (h*64 + dp)*128;
      float acc = wrow[lane]*qv[lane] + wrow[lane+64]*qv[lane+64];
#pragma unroll
      for (int off = 32; off > 0; off >>= 1) acc += __shfl_down(acc, off);
      if (lane == 0) qf[dp] = acc + bv[h*64 + dp];
    }
    __syncthreads();
    // phase 2: QK[e] = sum_dp qf[dp]*Wk[dp][e]
    if (tid < 128) {
      int e = tid;
      const float* Wk = W + (128 + h*64)*128 + e;
      float a0=0.f,a1=0.f,a2=0.f,a3=0.f;
      for (int dp = 0; dp < 64; dp += 4) {
        a0 += qf[dp+0] * Wk[(dp+0)*128];
        a1 += qf[dp+1] * Wk[(dp+1)*128];
        a2 += qf[dp+2] * Wk[(dp+2)*128];
        a3 += qf[dp+3] * Wk[(dp+3)*128];
      }
      wsf[(ens ? QK_ENS : QK_GRP) + bi*128 + e] = (a0+a1)+(a2+a3);
    }
    if (wave == 3) {                     // QB = qf . bk
      float acc = qf[lane] * bv[128 + h*64 + lane];
#pragma unroll
      for (int off = 32; off > 0; off >>= 1) acc += __shfl_down(acc, off);
      if (lane == 0) wsf[(ens ? QB_ENS : QB_GRP) + bi] = acc;
    }
  } else if (blk < 1584) {               // Mplain[gi][r][ep]
    int b2 = blk - 48;
    int gi = b2 >> 7, r = b2 & 127;
    int ep = tid, h = ep >> 7, e = ep & 127;
    const float* wo = gow + gi*16384 + r*128 + h*64;
    const float* wv = giw + gi*49152 + (256 + h*64)*128 + e;
    float a0=0.f,a1=0.f,a2=0.f,a3=0.f;
    for (int hd = 0; hd < 64; hd += 4) {
      a0 += wo[hd+0] * wv[(hd+0)*128];
      a1 += wo[hd+1] * wv[(hd+1)*128];
      a2 += wo[hd+2] * wv[(hd+2)*128];
      a3 += wo[hd+3] * wv[(hd+3)*128];
    }
    Mplain[(gi*128 + r)*256 + ep] = (a0+a1)+(a2+a3);
  } else if (blk < 1712) {               // MeB A-frag
    int f2 = (blk - 1584)*256 + tid;
    int r = f2 >> 8, ep = f2 & 255;
    int h = ep >> 7, e = ep & 127;
    const float* wo = eow + r*128 + h*64;
    const float* wv = eiw + (256 + h*64)*128 + e;
    float a0=0.f,a1=0.f,a2=0.f,a3=0.f;
    for (int hd = 0; hd < 64; hd += 4) {
      a0 += wo[hd+0] * wv[(hd+0)*128];
      a1 += wo[hd+1] * wv[(hd+1)*128];
      a2 += wo[hd+2] * wv[(hd+2)*128];
      a3 += wo[hd+3] * wv[(hd+3)*128];
    }
    float acc = (a0+a1)+(a2+a3);
    int mt = r >> 4, lr = r & 15, kt = ep >> 5, q = (ep >> 3) & 3, j = ep & 7;
    MeB[((mt*8 + kt)*64 + (q*16 + lr))*8 + j] = f2bf(acc);
  } else if (blk < 2096) {               // CGRP (1536 wave-tasks)
    int id = (blk - 1712)*4 + wave;
    int i = id >> 7, d = id & 127;
    const float* wrow = gow + i*16384 + d*128;
    const float* bvv = gib + i*384 + 256;
    float acc = wrow[lane]*bvv[lane] + wrow[lane+64]*bvv[lane+64];
#pragma unroll
    for (int off = 32; off > 0; off >>= 1) acc += __shfl_down(acc, off);
    if (lane == 0) wsf[CGRP + id] = acc + gob[i*128 + d];
  } else if (blk < 2128) {               // CENS (128 wave-tasks)
    int d = (blk - 2096)*4 + wave;
    const float* wrow = eow + d*128;
    const float* bvv = eib + 256;
    float acc = wrow[lane]*bvv[lane] + wrow[lane+64]*bvv[lane+64];
#pragma unroll
    for (int off = 32; off > 0; off >>= 1) acc += __shfl_down(acc, off);
    if (lane == 0) wsf[CENS + d] = acc + eob[d];
  } else {                               // F-zero: 19456 uint4
    int idx = (blk - 2128)*256 + tid;
    if (idx < 19456) ((uint4*)Fws)[idx] = (uint4){0,0,0,0};
  }
}

// ---------------------------------------------------------------------------
// P2: F-build (A-frags, 192 blocks) + qkeB (16) + cwq (52). Grid 260 x 256.
// ---------------------------------------------------------------------------
__global__ void hwe_p2(const float* __restrict__ cw, const float* __restrict__ cb,
                       const float* __restrict__ ce, const float* __restrict__ Mplain,
                       const float* __restrict__ wsf,
                       unsigned short* __restrict__ Fws,
                       unsigned short* __restrict__ qkeB, float* __restrict__ cwq) {
  int blk = blockIdx.x, tid = threadIdx.x;
  if (blk < 192) {                      // F_h[r][k] = sum_e M_h[r][e]*cw2[k][e]
    __shared__ __align__(16) unsigned short M16[16*130];
    __shared__ __align__(16) unsigned short cwl[85*130];
    int gi = blk >> 4, h = (blk >> 3) & 1, mt = blk & 7;
    int go = GOFF[gi], K5 = K5A[gi], S = SLOTS3[gi];
    int r0 = mt*16;
    for (int idx = tid; idx < 2048; idx += 256) {
      int rr = idx >> 7, e = idx & 127;
      M16[rr*130 + e] = f2bf(Mplain[(gi*128 + r0 + rr)*256 + h*128 + e]);
    }
    for (int idx = tid; idx < K5*128; idx += 256) {
      int k = idx >> 7, e = idx & 127;
      int q = (k*205) >> 10;
      int pp = k - q*5;
      int s = GSLOT[go + q];
      int v = (s < 45) ? s : s + 20;
      float val = (pp < 4) ? cw[(v*4 + pp)*128 + e] : (cb[v*128 + e] + ce[v*128 + e]);
      cwl[k*130 + e] = f2bf(val);
    }
    __syncthreads();
    const unsigned* M32 = (const unsigned*)M16;
    const unsigned* C32 = (const unsigned*)cwl;
    for (int o = tid; o < 16*K5; o += 256) {
      int k = o >> 4, rr = o & 15;
      float acc = 0.f;
#pragma unroll 8
      for (int e2 = 0; e2 < 64; ++e2) {
        unsigned m = M32[rr*65 + e2];
        unsigned c = C32[k*65 + e2];
        acc += __uint_as_float(m << 16) * __uint_as_float(c << 16);
        acc += __uint_as_float(m & 0xffff0000u) * __uint_as_float(c & 0xffff0000u);
      }
      int kpp = h*K5 + k;
      int ktl = kpp >> 5;
      int addr = (FOFFA[gi]*8 + mt*S + ktl)*512 + ((kpp >> 3) & 3)*128 + rr*8 + (kpp & 7);
      Fws[addr] = f2bf(acc);
    }
  } else if (blk < 208) {               // qkeB B-frag from QK_ENS
    int f4 = (blk - 192)*256 + tid;     // [0,4096)
    int lane = (f4 >> 3) & 63, j = f4 & 7;
    int th = ((f4 >> 11) & 1)*16 + (lane & 15);
    int kt = (f4 >> 9) & 3;
    float val = (th < 24) ? wsf[QK_ENS + th*128 + kt*32 + (lane >> 4)*8 + j] : 0.f;
    qkeB[f4] = f2bf(val);
  } else {                              // cwq: wave per (gg,h)
    int wid = (blk - 208)*4 + (tid >> 6);
    int lane = tid & 63;
    if (wid < 206) {
      int gg = wid >> 1, h = wid & 1;
      int gi = GIDX[gg];
      int s = GSLOT[gg];
      int v = (s < 45) ? s : s + 20;
      const float* qk = wsf + QK_GRP + (gi*2 + h)*128;
      float q0 = qk[lane], q1 = qk[lane + 64];
      float a[5];
#pragma unroll
      for (int pp = 0; pp < 4; ++pp)
        a[pp] = cw[(v*4 + pp)*128 + lane]*q0 + cw[(v*4 + pp)*128 + lane + 64]*q1;
      a[4] = (cb[v*128 + lane] + ce[v*128 + lane])*q0 +
             (cb[v*128 + lane + 64] + ce[v*128 + lane + 64])*q1;
#pragma unroll
      for (int off = 32; off > 0; off >>= 1)
#pragma unroll
        for (int kk = 0; kk < 5; ++kk) a[kk] += __shfl_down(a[kk], off);
      if (lane == 0) {
        float* o = cwq + (gg*2 + h)*8;
        o[0] = a[0]*0.125f; o[1] = a[1]*0.125f; o[2] = a[2]*0.125f; o[3] = a[3]*0.125f;
        o[4] = (a[4] + wsf[QB_GRP + gi*2 + h]) * 0.125f;
      }
    }
  }
}

// ---------------------------------------------------------------------------
// Main kernel. grid 1024, block 256 (4 waves). 8 patches per block.
// LDS (bytes), total 63168:
//   region0 [0,28672):
//     A/B: xpB@0 [8p][68][4]us 4352; scb@4352 [8p][2h][104]us 3328;
//          wpAll@7680 [20slot][64][8]us 20480  (ends 28160)
//     C:   Gl@0 [2lp][128r][40]us 20480 (stride 40 = conflict-free writes);
//          apB@20480 [8p][64][8]us 8192  (ends 28672)
//   outg2@28672 [104][136]us 28288   (rows 96..103 zeroed = s-phantom)
//   sce2@56960 [192][16]us 6144
//   stats@63104 float[16]
// ---------------------------------------------------------------------------
__global__ __launch_bounds__(256, 2) void hwe_main(
    const float* __restrict__ x,
    const float* __restrict__ lgam, const float* __restrict__ lbet,
    const float* __restrict__ wsf,  const float* __restrict__ cwq,
    const unsigned short* __restrict__ Fws, const unsigned short* __restrict__ MeB,
    const unsigned short* __restrict__ qkeB,
    float* __restrict__ out) {
  __shared__ __align__(16) unsigned char smem[63168];
  unsigned short* xpB   = (unsigned short*)(smem);
  unsigned short* scb   = (unsigned short*)(smem + 4352);
  unsigned short* wpAll = (unsigned short*)(smem + 7680);
  unsigned short* Gl    = (unsigned short*)(smem);          // C overlay
  unsigned short* apB   = (unsigned short*)(smem + 20480);  // C overlay
  unsigned short* outg2 = (unsigned short*)(smem + 28672);
  unsigned short* sce2  = (unsigned short*)(smem + 56960);
  float*          stats = (float*)(smem + 63104);

  const int tid  = threadIdx.x;
  const int wave = tid >> 6;
  const int lane = tid & 63;
  const int quad = lane >> 4;
  const int l15  = lane & 15;

  const int hi   = blockIdx.x >> 4;
  const int wib  = (blockIdx.x & 15) << 3;
  const int nbase = hi*128 + wib;

  // ---- A1: pixels + zero phantom outg2 rows 96..103 ----
  for (int idx = tid; idx < 2176; idx += 256) {
    int c = idx & 15, r = (idx >> 4) & 1, s = idx >> 5;
    int v = (s < 45) ? s : s + 20;
    float val = x[(v*128 + 2*hi + r)*256 + 2*wib + c];
    int p = c >> 1, pp = r*2 + (c & 1);
    xpB[(p*68 + s)*4 + pp] = f2bf(val);
  }
  for (int idx = tid; idx < 544; idx += 256)
    ((unsigned*)outg2)[96*68 + idx] = 0;
  __syncthreads();

  // ---- A2: group scores via cwq fold ----
  for (int idx = tid; idx < 1648; idx += 256) {
    int h = idx & 1, p = (idx >> 1) & 7, gg = idx >> 4;
    int s = GSLOT[gg];
    const float* c = cwq + (gg*2 + h)*8;
    const unsigned short* xr = xpB + (p*68 + s)*4;
    float acc = c[4] + bf2f(xr[0])*c[0] + bf2f(xr[1])*c[1]
                     + bf2f(xr[2])*c[2] + bf2f(xr[3])*c[3];
    scb[(p*2 + h)*104 + gg] = f2bf(acc);
  }
  __syncthreads();

  // ---- A3: softmax per (p,h,group) ----
  if (tid < 192) {
    int gi = tid % 12, h = (tid / 12) & 1, p = tid / 24;
    int go = GOFF[gi], G = GOFF[gi+1] - go;
    unsigned short* row = scb + (p*2 + h)*104 + go;
    float m = -1e30f;
    for (int g = 0; g < G; ++g) m = fmaxf(m, bf2f(row[g]));
    float ssum = 0.f;
    for (int g = 0; g < G; ++g) {
      float ev = __expf(bf2f(row[g]) - m);
      ssum += ev;
      row[g] = f2bf(ev);
    }
    float inv = 1.f / ssum;
    for (int g = 0; g < G; ++g) row[g] = f2bf(bf2f(row[g]) * inv);
  }
  __syncthreads();

  // ---- Phase B: two halves of 6 groups; F-folded single GEMM per group ----
  for (int hb = 0; hb < 2; ++hb) {
    const int nsl = hb ? 20 : 18;
    const int sbase = hb ? 18 : 0;
    for (int i = tid; i < nsl*64; i += 256)
      *(uint4*)(wpAll + i*8) = (uint4){0,0,0,0};
    __syncthreads();
    {
      const int total = hb ? 4720 : 3520;
      for (int idx = tid; idx < total; idx += 256) {
        int gil = 0;
#pragma unroll
        for (int t6 = 1; t6 < 6; ++t6) {
          int eo = hb ? EOFF1[t6] : EOFF0[t6];
          if (idx >= eo) gil = t6;
        }
        int gi = hb*6 + gil;
        int local = idx - (hb ? EOFF1[gil] : EOFF0[gil]);
        int kpp = local >> 3, p = local & 7;
        int K5 = K5A[gi];
        int h = (kpp >= K5) ? 1 : 0;
        int k = kpp - (h ? K5 : 0);
        int q = (k*205) >> 10;
        int pp = k - q*5;
        int gg = GOFF[gi] + q;
        float a = bf2f(scb[(p*2 + h)*104 + gg]);
        float val = (pp < 4) ? a * bf2f(xpB[(p*68 + GSLOT[gg])*4 + pp]) : a;
        int ls = (FOFFA[gi] - sbase) + (kpp >> 5);
        wpAll[ls*512 + ((kpp >> 3) & 3)*128 + p*8 + (kpp & 7)] = f2bf(val);
      }
    }
    __syncthreads();
    for (int i = 0; i < 12; ++i) {
      int pi = i*4 + wave;
      int gil = pi >> 3, mt = pi & 7;
      int gi = hb*6 + gil;
      int S = SLOTS3[gi];
      int lbase = FOFFA[gi] - sbase;
      f32x4 acc = {0.f,0.f,0.f,0.f};
      for (int kt = 0; kt < S; ++kt) {
        short8 a = *(const short8*)(Fws + (FOFFA[gi]*8 + mt*S + kt)*512 + lane*8);
        short8 b = *(const short8*)(wpAll + (lbase + kt)*512 + lane*8);
        acc = __builtin_amdgcn_mfma_f32_16x16x32_bf16(a, b, acc, 0, 0, 0);
      }
      if (l15 < 8) {
        int p = l15;
        int rb = mt*16 + quad*4;
        unsigned short t0 = f2bf(acc[0] + wsf[CGRP + gi*128 + rb + 0]);
        unsigned short t1 = f2bf(acc[1] + wsf[CGRP + gi*128 + rb + 1]);
        unsigned short t2 = f2bf(acc[2] + wsf[CGRP + gi*128 + rb + 2]);
        unsigned short t3 = f2bf(acc[3] + wsf[CGRP + gi*128 + rb + 3]);
        uint2 w;
        w.x = (unsigned)t0 | ((unsigned)t1 << 16);
        w.y = (unsigned)t2 | ((unsigned)t3 << 16);
        *(uint2*)(outg2 + (gi*8 + p)*136 + rb) = w;
      }
    }
    __syncthreads();
  }

  // ---- C1: ens scores GEMM (M=96 rows (s,p), N=24 (t,h), K=128) ----
  for (int ti = 0; ti < 3; ++ti) {
    int T = wave*3 + ti;
    int mtp = T >> 1, ntp = T & 1;
    f32x4 acc = {0.f,0.f,0.f,0.f};
#pragma unroll
    for (int kt = 0; kt < 4; ++kt) {
      short8 a = *(const short8*)(outg2 + (mtp*16 + l15)*136 + kt*32 + quad*8);
      short8 b = *(const short8*)(qkeB + ((ntp*4 + kt)*64 + lane)*8);
      acc = __builtin_amdgcn_mfma_f32_16x16x32_bf16(a, b, acc, 0, 0, 0);
    }
    int th = ntp*16 + l15;
    if (th < 24) {
      float qb = wsf[QB_ENS + th];
#pragma unroll
      for (int reg = 0; reg < 4; ++reg) {
        int rowE = mtp*16 + quad*4 + reg;
        sce2[((rowE & 7)*24 + th)*16 + (rowE >> 3)] = f2bf((acc[reg] + qb) * 0.125f);
      }
    }
  }
  __syncthreads();

  // ---- C2: softmax over s per (p, t, h) ----
  if (tid < 192) {
    unsigned short* row = sce2 + tid*16;
    float m = -1e30f;
    for (int s = 0; s < 12; ++s) m = fmaxf(m, bf2f(row[s]));
    float ssum = 0.f;
    for (int s = 0; s < 12; ++s) {
      float ev = __expf(bf2f(row[s]) - m);
      ssum += ev;
      row[s] = f2bf(ev);
    }
    float inv = 1.f / ssum;
    for (int s = 0; s < 12; ++s) row[s] = f2bf(bf2f(row[s]) * inv);
  }
  __syncthreads();

  // ---- apB: attn weights as B-frags ----
  for (int idx = tid; idx < 4096; idx += 256) {
    int p = idx >> 9, r9 = idx & 511;
    int ln = r9 >> 3, j = r9 & 7;
    int t = ln & 15, qd = ln >> 4;
    int kpp = qd*8 + j;
    int h = kpp >> 4, s = kpp & 15;
    unsigned short v = 0;
    if (s < 12 && t < 12) v = sce2[(p*24 + t*2 + h)*16 + s];
    apB[p*512 + ln*8 + j] = v;
  }
  // preload cens + MeB fragments (reused across all 4 C3 periods)
  float cens0[4], cens1[4];
#pragma unroll
  for (int reg = 0; reg < 4; ++reg) {
    cens0[reg] = wsf[CENS + (wave*2 + 0)*16 + quad*4 + reg];
    cens1[reg] = wsf[CENS + (wave*2 + 1)*16 + quad*4 + reg];
  }
  short8 meAr[16];   // [mi][h][kt]
#pragma unroll
  for (int mi = 0; mi < 2; ++mi)
#pragma unroll
    for (int h = 0; h < 2; ++h)
#pragma unroll
      for (int kt = 0; kt < 4; ++kt)
        meAr[(mi*2 + h)*4 + kt] =
          *(const short8*)(MeB + (((wave*2 + mi)*8 + h*4 + kt)*64 + lane)*8);
  __syncthreads();

  // ---- C3: 2 patches per period: G-GEMM -> R-GEMM -> register LayerNorm ----
  for (int pp2 = 0; pp2 < 4; ++pp2) {
    f32x4 g[2][2][2];  // [lp][mi][h]
#pragma unroll
    for (int lp = 0; lp < 2; ++lp)
#pragma unroll
      for (int mi = 0; mi < 2; ++mi)
#pragma unroll
        for (int h = 0; h < 2; ++h) g[lp][mi][h] = (f32x4){0.f,0.f,0.f,0.f};
#pragma unroll
    for (int lp = 0; lp < 2; ++lp) {
      int p = pp2*2 + lp;
      int brow = (l15 < 12 ? l15 : 12)*8 + p;   // phantom s -> zero row 96+p
#pragma unroll
      for (int h = 0; h < 2; ++h) {
#pragma unroll
        for (int kt = 0; kt < 4; ++kt) {
          short8 b = *(const short8*)(outg2 + brow*136 + kt*32 + quad*8);
          g[lp][0][h] = __builtin_amdgcn_mfma_f32_16x16x32_bf16(
              meAr[(0*2 + h)*4 + kt], b, g[lp][0][h], 0, 0, 0);
          g[lp][1][h] = __builtin_amdgcn_mfma_f32_16x16x32_bf16(
              meAr[(1*2 + h)*4 + kt], b, g[lp][1][h], 0, 0, 0);
        }
      }
    }
    // write G to LDS: Gl[lp][r][h*16+s], row stride 40 (conflict-free)
#pragma unroll
    for (int lp = 0; lp < 2; ++lp)
#pragma unroll
      for (int mi = 0; mi < 2; ++mi)
#pragma unroll
        for (int h = 0; h < 2; ++h)
#pragma unroll
          for (int reg = 0; reg < 4; ++reg) {
            int r = (wave*2 + mi)*16 + quad*4 + reg;
            Gl[lp*5120 + r*40 + h*16 + l15] = f2bf(g[lp][mi][h][reg]);
          }
    __syncthreads();

    // R-GEMM: R[r][t] = G @ a'  (K=32)
    f32x4 rr[2][2];
    float s1[2] = {0.f, 0.f}, s2[2] = {0.f, 0.f};
#pragma unroll
    for (int lp = 0; lp < 2; ++lp) {
      int p = pp2*2 + lp;
      short8 bfrag = *(const short8*)(apB + p*512 + lane*8);
#pragma unroll
      for (int mi = 0; mi < 2; ++mi) {
        int mt2 = wave*2 + mi;
        short8 afrag = *(const short8*)(Gl + lp*5120 + (mt2*16 + l15)*40 + quad*8);
        f32x4 acc = {0.f,0.f,0.f,0.f};
        acc = __builtin_amdgcn_mfma_f32_16x16x32_bf16(afrag, bfrag, acc, 0, 0, 0);
#pragma unroll
        for (int reg = 0; reg < 4; ++reg)
          acc[reg] += (mi ? cens1[reg] : cens0[reg]);
        rr[lp][mi] = acc;
        if (l15 < 12) {
#pragma unroll
          for (int reg = 0; reg < 4; ++reg) {
            float v = acc[reg];
            s1[lp] += v; s2[lp] += v*v;
          }
        }
      }
    }
#pragma unroll
    for (int off = 32; off > 0; off >>= 1) {
#pragma unroll
      for (int lp = 0; lp < 2; ++lp) {
        s1[lp] += __shfl_xor(s1[lp], off);
        s2[lp] += __shfl_xor(s2[lp], off);
      }
    }
    if (lane == 0) {
#pragma unroll
      for (int lp = 0; lp < 2; ++lp) {
        stats[lp*4 + wave] = s1[lp];
        stats[8 + lp*4 + wave] = s2[lp];
      }
    }
    __syncthreads();
#pragma unroll
    for (int lp = 0; lp < 2; ++lp) {
      float t1 = stats[lp*4+0] + stats[lp*4+1] + stats[lp*4+2] + stats[lp*4+3];
      float t2 = stats[8+lp*4+0] + stats[8+lp*4+1] + stats[8+lp*4+2] + stats[8+lp*4+3];
      float mean = t1 * (1.f/1536.f);
      float var  = t2 * (1.f/1536.f) - mean*mean;
      float rstd = rsqrtf(var + 1e-5f);
      if (l15 < 12) {
        long nrow = (long)(nbase + pp2*2 + lp) * 1536;
#pragma unroll
        for (int mi = 0; mi < 2; ++mi) {
          int rb = (wave*2 + mi)*16 + quad*4;
          int j = l15*128 + rb;
          float4 gm = *(const float4*)(lgam + j);
          float4 bt = *(const float4*)(lbet + j);
          float4 o;
          o.x = (rr[lp][mi][0] - mean)*rstd*gm.x + bt.x;
          o.y = (rr[lp][mi][1] - mean)*rstd*gm.y + bt.y;
          o.z = (rr[lp][mi][2] - mean)*rstd*gm.z + bt.z;
          o.w = (rr[lp][mi][3] - mean)*rstd*gm.w + bt.w;
          *(float4*)(out + nrow + j) = o;
        }
      }
    }
    __syncthreads();
  }
}

// ---------------------------------------------------------------------------
extern "C" void kernel_launch(void* const* d_in, const int* in_sizes, int n_in,
                              void* d_out, int out_size, void* d_ws, size_t ws_size,
                              hipStream_t stream) {
  const float* x   = (const float*)d_in[0];
  const float* cw  = (const float*)d_in[1];
  const float* cb  = (const float*)d_in[2];
  const float* ce  = (const float*)d_in[3];
  const float* cq  = (const float*)d_in[4];
  const float* giw = (const float*)d_in[5];
  const float* gib = (const float*)d_in[6];
  const float* gow = (const float*)d_in[7];
  const float* gob = (const float*)d_in[8];
  const float* eq  = (const float*)d_in[9];
  const float* eiw = (const float*)d_in[10];
  const float* eib = (const float*)d_in[11];
  const float* eow = (const float*)d_in[12];
  const float* eob = (const float*)d_in[13];
  const float* lg  = (const float*)d_in[14];
  const float* lb  = (const float*)d_in[15];

  float* wsf = (float*)d_ws;
  float* cwq = (float*)((char*)d_ws + CWQ_BYTE);
  float* Mplain = (float*)((char*)d_ws + MPL_BYTE);
  unsigned short* MeB  = (unsigned short*)((char*)d_ws + MEB_BYTE);
  unsigned short* qkeB = (unsigned short*)((char*)d_ws + QKEB_BYTE);
  unsigned short* Fws  = (unsigned short*)((char*)d_ws + FWS_BYTE);

  hwe_p1<<<2204, 256, 0, stream>>>(giw, gib, gow, gob, cq, eq, eiw, eib, eow, eob,
                                   wsf, Mplain, MeB, Fws);
  hwe_p2<<<260, 256, 0, stream>>>(cw, cb, ce, Mplain, wsf, Fws, qkeB, cwq);
  hwe_main<<<1024, 256, 0, stream>>>(x, lg, lb, wsf, cwq, Fws, MeB, qkeB,
                                     (float*)d_out);
}